// Round 3
// baseline (534.684 us; speedup 1.0000x reference)
//
#include <hip/hip_runtime.h>
#include <math.h>

#define N_NODES 32768
#define E_EDGES 1048576
#define CIN 128
#define CHID 256
#define COUT 128

// ---------------------------------------------------------------------------
// CSR build: deg count -> exclusive scan (+dinv) -> fill
// ---------------------------------------------------------------------------
__global__ __launch_bounds__(256) void deg_kernel(const int* __restrict__ dst,
                                                  int* __restrict__ deg) {
    int e = blockIdx.x * blockDim.x + threadIdx.x;
    if (e < E_EDGES) atomicAdd(&deg[dst[e]], 1);
}

__global__ __launch_bounds__(1024) void scan_kernel(const int* __restrict__ deg,
                                                    int* __restrict__ offs,
                                                    int* __restrict__ cursor,
                                                    float* __restrict__ dinv) {
    __shared__ int s[1024];
    int t = threadIdx.x;
    int base = t * 32;  // 1024 threads x 32 = 32768
    int ts = 0;
#pragma unroll
    for (int j = 0; j < 32; ++j) ts += deg[base + j];
    s[t] = ts;
    __syncthreads();
    // Hillis-Steele inclusive scan over 1024 thread-sums (double-barrier form)
    for (int off = 1; off < 1024; off <<= 1) {
        int v = (t >= off) ? s[t - off] : 0;
        __syncthreads();
        s[t] += v;
        __syncthreads();
    }
    int run = s[t] - ts;  // exclusive prefix for this chunk
    for (int j = 0; j < 32; ++j) {
        int idx = base + j;
        int d = deg[idx];
        offs[idx] = run;
        cursor[idx] = run;
        // reference deg includes the self-loop: indeg + 1 (always >= 1)
        dinv[idx] = 1.0f / sqrtf((float)(d + 1));
        run += d;
    }
    if (t == 1023) offs[N_NODES] = s[1023];
}

__global__ __launch_bounds__(256) void fill_kernel(const int* __restrict__ src,
                                                   const int* __restrict__ dst,
                                                   int* __restrict__ cursor,
                                                   int* __restrict__ csr) {
    int e = blockIdx.x * blockDim.x + threadIdx.x;
    if (e < E_EDGES) {
        int d = dst[e];
        int pos = atomicAdd(&cursor[d], 1);
        csr[pos] = src[e];
    }
}

// ---------------------------------------------------------------------------
// GEMM1: g1[i][c] = (x[i,:] @ W1[:,c]) * dinv[i]        (pre-scaled by dinv)
// 64 rows/block (16 rows/wave) to amortize W1 L2 traffic; xs broadcast-read.
// ---------------------------------------------------------------------------
__global__ __launch_bounds__(256) void gemm1_kernel(const float* __restrict__ x,
                                                    const float* __restrict__ W1,
                                                    const float* __restrict__ dinv,
                                                    float* __restrict__ g1) {
    __shared__ float xs[64][CIN];  // 32 KB
    int tid = threadIdx.x;
    int rowBase = blockIdx.x * 64;

    // cooperative load of 64x128 f32 tile (contiguous 32 KB)
    const float4* xg = (const float4*)(x + (size_t)rowBase * CIN);
    float4* xsv = (float4*)(&xs[0][0]);
#pragma unroll
    for (int j = 0; j < 8; ++j) xsv[tid + j * 256] = xg[tid + j * 256];
    __syncthreads();

    int wave = tid >> 6, lane = tid & 63;
    int c0 = lane * 4;   // 64 lanes x 4 = 256 output channels
    int r0 = wave * 16;

    float4 acc[16];
#pragma unroll
    for (int r = 0; r < 16; ++r) acc[r] = make_float4(0.f, 0.f, 0.f, 0.f);

    for (int k = 0; k < CIN; k += 4) {
        float4 w0 = *(const float4*)(&W1[(k + 0) * CHID + c0]);
        float4 w1 = *(const float4*)(&W1[(k + 1) * CHID + c0]);
        float4 w2 = *(const float4*)(&W1[(k + 2) * CHID + c0]);
        float4 w3 = *(const float4*)(&W1[(k + 3) * CHID + c0]);
#pragma unroll
        for (int r = 0; r < 16; ++r) {
            float4 xv = *(const float4*)(&xs[r0 + r][k]);
            acc[r].x += xv.x * w0.x + xv.y * w1.x + xv.z * w2.x + xv.w * w3.x;
            acc[r].y += xv.x * w0.y + xv.y * w1.y + xv.z * w2.y + xv.w * w3.y;
            acc[r].z += xv.x * w0.z + xv.y * w1.z + xv.z * w2.z + xv.w * w3.z;
            acc[r].w += xv.x * w0.w + xv.y * w1.w + xv.z * w2.w + xv.w * w3.w;
        }
    }

#pragma unroll
    for (int r = 0; r < 16; ++r) {
        int row = rowBase + r0 + r;
        float dv = dinv[row];
        float4 o;
        o.x = acc[r].x * dv; o.y = acc[r].y * dv;
        o.z = acc[r].z * dv; o.w = acc[r].w * dv;
        *(float4*)(&g1[(size_t)row * CHID + c0]) = o;
    }
}

// ---------------------------------------------------------------------------
// AGG1: h1[i] = dinv[i]*(sum_{e:dst=i} g1[src] + g1[i]) + b1
// one wave per node; lane owns 4 fixed channels; 8-way unrolled gathers for
// MLP (8 independent 1KB row loads in flight per wave); BN stats in registers.
// ---------------------------------------------------------------------------
__global__ __launch_bounds__(256) void agg1_kernel(const float* __restrict__ g1,
                                                   const int* __restrict__ offs,
                                                   const int* __restrict__ csr,
                                                   const float* __restrict__ dinv,
                                                   const float* __restrict__ b1,
                                                   float* __restrict__ h1,
                                                   float* __restrict__ stats) {
    int tid = threadIdx.x, wave = tid >> 6, lane = tid & 63;
    int c0 = lane * 4;
    float4 b = *(const float4*)(&b1[c0]);
    float4 ps = make_float4(0.f, 0.f, 0.f, 0.f);
    float4 pq = make_float4(0.f, 0.f, 0.f, 0.f);

    for (int g = blockIdx.x; g < N_NODES / 4; g += gridDim.x) {
        int node = g * 4 + wave;
        int s0 = offs[node], s1 = offs[node + 1];
        // self loop contribution
        float4 acc = *(const float4*)(&g1[(size_t)node * CHID + c0]);
        int d = s0;
        for (; d + 8 <= s1; d += 8) {
            int i0 = csr[d + 0], i1 = csr[d + 1], i2 = csr[d + 2], i3 = csr[d + 3];
            int i4 = csr[d + 4], i5 = csr[d + 5], i6 = csr[d + 6], i7 = csr[d + 7];
            float4 v0 = *(const float4*)(&g1[(size_t)i0 * CHID + c0]);
            float4 v1 = *(const float4*)(&g1[(size_t)i1 * CHID + c0]);
            float4 v2 = *(const float4*)(&g1[(size_t)i2 * CHID + c0]);
            float4 v3 = *(const float4*)(&g1[(size_t)i3 * CHID + c0]);
            float4 v4 = *(const float4*)(&g1[(size_t)i4 * CHID + c0]);
            float4 v5 = *(const float4*)(&g1[(size_t)i5 * CHID + c0]);
            float4 v6 = *(const float4*)(&g1[(size_t)i6 * CHID + c0]);
            float4 v7 = *(const float4*)(&g1[(size_t)i7 * CHID + c0]);
            acc.x += ((v0.x + v1.x) + (v2.x + v3.x)) + ((v4.x + v5.x) + (v6.x + v7.x));
            acc.y += ((v0.y + v1.y) + (v2.y + v3.y)) + ((v4.y + v5.y) + (v6.y + v7.y));
            acc.z += ((v0.z + v1.z) + (v2.z + v3.z)) + ((v4.z + v5.z) + (v6.z + v7.z));
            acc.w += ((v0.w + v1.w) + (v2.w + v3.w)) + ((v4.w + v5.w) + (v6.w + v7.w));
        }
        for (; d < s1; ++d) {
            int s = csr[d];
            float4 v = *(const float4*)(&g1[(size_t)s * CHID + c0]);
            acc.x += v.x; acc.y += v.y; acc.z += v.z; acc.w += v.w;
        }
        float dv = dinv[node];
        float4 h;
        h.x = acc.x * dv + b.x; h.y = acc.y * dv + b.y;
        h.z = acc.z * dv + b.z; h.w = acc.w * dv + b.w;
        *(float4*)(&h1[(size_t)node * CHID + c0]) = h;
        ps.x += h.x; ps.y += h.y; ps.z += h.z; ps.w += h.w;
        pq.x += h.x * h.x; pq.y += h.y * h.y; pq.z += h.z * h.z; pq.w += h.w * h.w;
    }

    // block-level reduce of BN partial stats, then one atomic per channel
    __shared__ float red[4][CHID];  // 4 KB
    *(float4*)(&red[wave][c0]) = ps;
    __syncthreads();
    {
        int c = tid;  // 0..255
        float v = red[0][c] + red[1][c] + red[2][c] + red[3][c];
        atomicAdd(&stats[c], v);
    }
    __syncthreads();
    *(float4*)(&red[wave][c0]) = pq;
    __syncthreads();
    {
        int c = tid;
        float v = red[0][c] + red[1][c] + red[2][c] + red[3][c];
        atomicAdd(&stats[CHID + c], v);
    }
}

// ---------------------------------------------------------------------------
// BN prep: per-channel affine a*h+bb equivalent to BN(gamma,beta)
// ---------------------------------------------------------------------------
__global__ __launch_bounds__(256) void bnprep_kernel(const float* __restrict__ stats,
                                                     const float* __restrict__ gamma,
                                                     const float* __restrict__ beta,
                                                     float* __restrict__ ab) {
    int c = threadIdx.x;
    float mean = stats[c] * (1.0f / N_NODES);
    float var = stats[CHID + c] * (1.0f / N_NODES) - mean * mean;
    float a = gamma[c] / sqrtf(var + 1e-5f);
    ab[c] = a;
    ab[CHID + c] = beta[c] - mean * a;
}

// ---------------------------------------------------------------------------
// GEMM2: g2[i][o] = dinv[i] * ( relu(a*h1[i,:]+bb) @ W2[:,o] )
// affine+relu applied while staging rows into LDS; 64 rows/block.
// ---------------------------------------------------------------------------
__global__ __launch_bounds__(256) void gemm2_kernel(const float* __restrict__ h1,
                                                    const float* __restrict__ ab,
                                                    const float* __restrict__ W2,
                                                    const float* __restrict__ dinv,
                                                    float* __restrict__ g2) {
    __shared__ float xs[64][CHID];  // 64 KB
    int tid = threadIdx.x;
    int rowBase = blockIdx.x * 64;

    // (tid + j*256) & 63 == tid & 63  ->  affine coeffs are loop-invariant
    int c4 = (tid & 63) * 4;
    float4 a4 = *(const float4*)(&ab[c4]);
    float4 b4 = *(const float4*)(&ab[CHID + c4]);

    const float4* hg = (const float4*)(h1 + (size_t)rowBase * CHID);
#pragma unroll
    for (int j = 0; j < 16; ++j) {
        int idx = tid + j * 256;          // 4096 float4s = 64x256 floats
        float4 v = hg[idx];
        float4 r;
        r.x = fmaxf(v.x * a4.x + b4.x, 0.f);
        r.y = fmaxf(v.y * a4.y + b4.y, 0.f);
        r.z = fmaxf(v.z * a4.z + b4.z, 0.f);
        r.w = fmaxf(v.w * a4.w + b4.w, 0.f);
        ((float4*)(&xs[0][0]))[idx] = r;
    }
    __syncthreads();

    int wave = tid >> 6, lane = tid & 63;
    int o0 = lane * 2;  // 64 lanes x 2 = 128 outputs
    int r0 = wave * 16;

    float2 acc[16];
#pragma unroll
    for (int r = 0; r < 16; ++r) acc[r] = make_float2(0.f, 0.f);

    for (int k = 0; k < CHID; k += 4) {
        float2 w0 = *(const float2*)(&W2[(k + 0) * COUT + o0]);
        float2 w1 = *(const float2*)(&W2[(k + 1) * COUT + o0]);
        float2 w2 = *(const float2*)(&W2[(k + 2) * COUT + o0]);
        float2 w3 = *(const float2*)(&W2[(k + 3) * COUT + o0]);
#pragma unroll
        for (int r = 0; r < 16; ++r) {
            float4 xv = *(const float4*)(&xs[r0 + r][k]);
            acc[r].x += xv.x * w0.x + xv.y * w1.x + xv.z * w2.x + xv.w * w3.x;
            acc[r].y += xv.x * w0.y + xv.y * w1.y + xv.z * w2.y + xv.w * w3.y;
        }
    }

#pragma unroll
    for (int r = 0; r < 16; ++r) {
        int row = rowBase + r0 + r;
        float dv = dinv[row];
        float2 o;
        o.x = acc[r].x * dv; o.y = acc[r].y * dv;
        *(float2*)(&g2[(size_t)row * COUT + o0]) = o;
    }
}

// ---------------------------------------------------------------------------
// AGG2: out[i] = dinv[i]*(sum g2[src] + g2[i]) + b2   (8-way unrolled gathers)
// ---------------------------------------------------------------------------
__global__ __launch_bounds__(256) void agg2_kernel(const float* __restrict__ g2,
                                                   const int* __restrict__ offs,
                                                   const int* __restrict__ csr,
                                                   const float* __restrict__ dinv,
                                                   const float* __restrict__ b2,
                                                   float* __restrict__ out) {
    int tid = threadIdx.x, wave = tid >> 6, lane = tid & 63;
    int c0 = lane * 2;
    float2 b = *(const float2*)(&b2[c0]);

    for (int g = blockIdx.x; g < N_NODES / 4; g += gridDim.x) {
        int node = g * 4 + wave;
        int s0 = offs[node], s1 = offs[node + 1];
        float2 acc = *(const float2*)(&g2[(size_t)node * COUT + c0]);  // self loop
        int d = s0;
        for (; d + 8 <= s1; d += 8) {
            int i0 = csr[d + 0], i1 = csr[d + 1], i2 = csr[d + 2], i3 = csr[d + 3];
            int i4 = csr[d + 4], i5 = csr[d + 5], i6 = csr[d + 6], i7 = csr[d + 7];
            float2 v0 = *(const float2*)(&g2[(size_t)i0 * COUT + c0]);
            float2 v1 = *(const float2*)(&g2[(size_t)i1 * COUT + c0]);
            float2 v2 = *(const float2*)(&g2[(size_t)i2 * COUT + c0]);
            float2 v3 = *(const float2*)(&g2[(size_t)i3 * COUT + c0]);
            float2 v4 = *(const float2*)(&g2[(size_t)i4 * COUT + c0]);
            float2 v5 = *(const float2*)(&g2[(size_t)i5 * COUT + c0]);
            float2 v6 = *(const float2*)(&g2[(size_t)i6 * COUT + c0]);
            float2 v7 = *(const float2*)(&g2[(size_t)i7 * COUT + c0]);
            acc.x += ((v0.x + v1.x) + (v2.x + v3.x)) + ((v4.x + v5.x) + (v6.x + v7.x));
            acc.y += ((v0.y + v1.y) + (v2.y + v3.y)) + ((v4.y + v5.y) + (v6.y + v7.y));
        }
        for (; d < s1; ++d) {
            int s = csr[d];
            float2 v = *(const float2*)(&g2[(size_t)s * COUT + c0]);
            acc.x += v.x; acc.y += v.y;
        }
        float dv = dinv[node];
        float2 o;
        o.x = acc.x * dv + b.x;
        o.y = acc.y * dv + b.y;
        *(float2*)(&out[(size_t)node * COUT + c0]) = o;
    }
}

// ---------------------------------------------------------------------------
extern "C" void kernel_launch(void* const* d_in, const int* in_sizes, int n_in,
                              void* d_out, int out_size, void* d_ws, size_t ws_size,
                              hipStream_t stream) {
    const float* x     = (const float*)d_in[0];
    const int*   ei    = (const int*)d_in[1];
    const float* W1    = (const float*)d_in[2];
    const float* b1    = (const float*)d_in[3];
    const float* gamma = (const float*)d_in[4];
    const float* beta  = (const float*)d_in[5];
    const float* W2    = (const float*)d_in[6];
    const float* b2    = (const float*)d_in[7];
    float* out = (float*)d_out;

    const int* srcv = ei;            // edge_index[0]
    const int* dstv = ei + E_EDGES;  // edge_index[1]

    // workspace layout (g2 aliases g1: g1 dead after agg1)
    char* ws = (char*)d_ws;
    size_t off = 0;
    auto alloc = [&](size_t bytes) -> void* {
        void* p = ws + off;
        off += (bytes + 255) & ~(size_t)255;
        return p;
    };
    int*   deg    = (int*)alloc((size_t)N_NODES * 4);
    int*   offs   = (int*)alloc((size_t)(N_NODES + 1) * 4);
    int*   cursor = (int*)alloc((size_t)N_NODES * 4);
    float* dinv   = (float*)alloc((size_t)N_NODES * 4);
    int*   csr    = (int*)alloc((size_t)E_EDGES * 4);
    float* g1     = (float*)alloc((size_t)N_NODES * CHID * 4);  // also g2
    float* h1     = (float*)alloc((size_t)N_NODES * CHID * 4);
    float* stats  = (float*)alloc(2 * CHID * 4);
    float* ab     = (float*)alloc(2 * CHID * 4);
    float* g2     = g1;

    hipMemsetAsync(deg, 0, (size_t)N_NODES * 4, stream);
    hipMemsetAsync(stats, 0, 2 * CHID * 4, stream);

    deg_kernel<<<E_EDGES / 256, 256, 0, stream>>>(dstv, deg);
    scan_kernel<<<1, 1024, 0, stream>>>(deg, offs, cursor, dinv);
    fill_kernel<<<E_EDGES / 256, 256, 0, stream>>>(srcv, dstv, cursor, csr);

    gemm1_kernel<<<N_NODES / 64, 256, 0, stream>>>(x, W1, dinv, g1);
    agg1_kernel<<<2048, 256, 0, stream>>>(g1, offs, csr, dinv, b1, h1, stats);
    bnprep_kernel<<<1, 256, 0, stream>>>(stats, gamma, beta, ab);
    gemm2_kernel<<<N_NODES / 64, 256, 0, stream>>>(h1, ab, W2, dinv, g2);
    agg2_kernel<<<2048, 256, 0, stream>>>(g2, offs, csr, dinv, b2, out);
}

// Round 4
// 534.600 us; speedup vs baseline: 1.0002x; 1.0002x over previous
//
#include <hip/hip_runtime.h>
#include <math.h>

#define N_NODES 32768
#define E_EDGES 1048576
#define CIN 128
#define CHID 256
#define COUT 128

// ---------------------------------------------------------------------------
// CSR build: deg count -> exclusive scan (+dinv) -> fill
// ---------------------------------------------------------------------------
__global__ __launch_bounds__(256) void deg_kernel(const int* __restrict__ dst,
                                                  int* __restrict__ deg) {
    int e = blockIdx.x * blockDim.x + threadIdx.x;
    if (e < E_EDGES) atomicAdd(&deg[dst[e]], 1);
}

__global__ __launch_bounds__(1024) void scan_kernel(const int* __restrict__ deg,
                                                    int* __restrict__ offs,
                                                    int* __restrict__ cursor,
                                                    float* __restrict__ dinv) {
    __shared__ int s[1024];
    int t = threadIdx.x;
    int base = t * 32;  // 1024 threads x 32 = 32768
    int ts = 0;
#pragma unroll
    for (int j = 0; j < 32; ++j) ts += deg[base + j];
    s[t] = ts;
    __syncthreads();
    // Hillis-Steele inclusive scan over 1024 thread-sums (double-barrier form)
    for (int off = 1; off < 1024; off <<= 1) {
        int v = (t >= off) ? s[t - off] : 0;
        __syncthreads();
        s[t] += v;
        __syncthreads();
    }
    int run = s[t] - ts;  // exclusive prefix for this chunk
    for (int j = 0; j < 32; ++j) {
        int idx = base + j;
        int d = deg[idx];
        offs[idx] = run;
        cursor[idx] = run;
        // reference deg includes the self-loop: indeg + 1 (always >= 1)
        dinv[idx] = 1.0f / sqrtf((float)(d + 1));
        run += d;
    }
    if (t == 1023) offs[N_NODES] = s[1023];
}

__global__ __launch_bounds__(256) void fill_kernel(const int* __restrict__ src,
                                                   const int* __restrict__ dst,
                                                   int* __restrict__ cursor,
                                                   int* __restrict__ csr) {
    int e = blockIdx.x * blockDim.x + threadIdx.x;
    if (e < E_EDGES) {
        int d = dst[e];
        int pos = atomicAdd(&cursor[d], 1);
        csr[pos] = src[e];
    }
}

// ---------------------------------------------------------------------------
// GEMM1: g1[i][c] = (x[i,:] @ W1[:,c]) * dinv[i]        (pre-scaled by dinv)
// 64 rows/block (16 rows/wave) to amortize W1 L2 traffic; xs broadcast-read.
// ---------------------------------------------------------------------------
__global__ __launch_bounds__(256) void gemm1_kernel(const float* __restrict__ x,
                                                    const float* __restrict__ W1,
                                                    const float* __restrict__ dinv,
                                                    float* __restrict__ g1) {
    __shared__ float xs[64][CIN];  // 32 KB
    int tid = threadIdx.x;
    int rowBase = blockIdx.x * 64;

    // cooperative load of 64x128 f32 tile (contiguous 32 KB)
    const float4* xg = (const float4*)(x + (size_t)rowBase * CIN);
    float4* xsv = (float4*)(&xs[0][0]);
#pragma unroll
    for (int j = 0; j < 8; ++j) xsv[tid + j * 256] = xg[tid + j * 256];
    __syncthreads();

    int wave = tid >> 6, lane = tid & 63;
    int c0 = lane * 4;   // 64 lanes x 4 = 256 output channels
    int r0 = wave * 16;

    float4 acc[16];
#pragma unroll
    for (int r = 0; r < 16; ++r) acc[r] = make_float4(0.f, 0.f, 0.f, 0.f);

    for (int k = 0; k < CIN; k += 4) {
        float4 w0 = *(const float4*)(&W1[(k + 0) * CHID + c0]);
        float4 w1 = *(const float4*)(&W1[(k + 1) * CHID + c0]);
        float4 w2 = *(const float4*)(&W1[(k + 2) * CHID + c0]);
        float4 w3 = *(const float4*)(&W1[(k + 3) * CHID + c0]);
#pragma unroll
        for (int r = 0; r < 16; ++r) {
            float4 xv = *(const float4*)(&xs[r0 + r][k]);
            acc[r].x += xv.x * w0.x + xv.y * w1.x + xv.z * w2.x + xv.w * w3.x;
            acc[r].y += xv.x * w0.y + xv.y * w1.y + xv.z * w2.y + xv.w * w3.y;
            acc[r].z += xv.x * w0.z + xv.y * w1.z + xv.z * w2.z + xv.w * w3.z;
            acc[r].w += xv.x * w0.w + xv.y * w1.w + xv.z * w2.w + xv.w * w3.w;
        }
    }

#pragma unroll
    for (int r = 0; r < 16; ++r) {
        int row = rowBase + r0 + r;
        float dv = dinv[row];
        float4 o;
        o.x = acc[r].x * dv; o.y = acc[r].y * dv;
        o.z = acc[r].z * dv; o.w = acc[r].w * dv;
        *(float4*)(&g1[(size_t)row * CHID + c0]) = o;
    }
}

// ---------------------------------------------------------------------------
// AGG1: h1[i] = dinv[i]*(sum_{e:dst=i} g1[src] + g1[i]) + b1
// one wave per node; lane owns 4 channels. 8-deep gather batches with the
// NEXT batch's csr indices prefetched before consuming the current gathers
// (breaks the s_load->gather dependency chain). launch_bounds(256,4) gives
// a 128-VGPR budget so all 8 float4 gathers stay in flight (R3 had VGPR=40
// -> compiler serialized the unroll; agg1 was latency-bound at 3.4 TB/s).
// ---------------------------------------------------------------------------
__global__ __launch_bounds__(256, 4) void agg1_kernel(const float* __restrict__ g1,
                                                      const int* __restrict__ offs,
                                                      const int* __restrict__ csr,
                                                      const float* __restrict__ dinv,
                                                      const float* __restrict__ b1,
                                                      float* __restrict__ h1,
                                                      float* __restrict__ stats) {
    int tid = threadIdx.x, wave = tid >> 6, lane = tid & 63;
    int c0 = lane * 4;
    float4 b = *(const float4*)(&b1[c0]);
    float4 ps = make_float4(0.f, 0.f, 0.f, 0.f);
    float4 pq = make_float4(0.f, 0.f, 0.f, 0.f);

    for (int g = blockIdx.x; g < N_NODES / 4; g += gridDim.x) {
        int node = g * 4 + wave;
        int s0 = offs[node], s1 = offs[node + 1];
        // self loop contribution
        float4 acc = *(const float4*)(&g1[(size_t)node * CHID + c0]);

        int nb = (s1 - s0) >> 3;  // full 8-batches
        int d = s0;
        int i0 = 0, i1 = 0, i2 = 0, i3 = 0, i4 = 0, i5 = 0, i6 = 0, i7 = 0;
        if (nb > 0) {
            i0 = csr[d + 0]; i1 = csr[d + 1]; i2 = csr[d + 2]; i3 = csr[d + 3];
            i4 = csr[d + 4]; i5 = csr[d + 5]; i6 = csr[d + 6]; i7 = csr[d + 7];
        }
        for (int t = 0; t < nb; ++t) {
            // issue 8 independent 1KB row gathers
            float4 v0 = *(const float4*)(&g1[(size_t)i0 * CHID + c0]);
            float4 v1 = *(const float4*)(&g1[(size_t)i1 * CHID + c0]);
            float4 v2 = *(const float4*)(&g1[(size_t)i2 * CHID + c0]);
            float4 v3 = *(const float4*)(&g1[(size_t)i3 * CHID + c0]);
            float4 v4 = *(const float4*)(&g1[(size_t)i4 * CHID + c0]);
            float4 v5 = *(const float4*)(&g1[(size_t)i5 * CHID + c0]);
            float4 v6 = *(const float4*)(&g1[(size_t)i6 * CHID + c0]);
            float4 v7 = *(const float4*)(&g1[(size_t)i7 * CHID + c0]);
            // prefetch next batch's indices while gathers are in flight
            int nd = d + 8;
            int j0 = 0, j1 = 0, j2 = 0, j3 = 0, j4 = 0, j5 = 0, j6 = 0, j7 = 0;
            if (t + 1 < nb) {
                j0 = csr[nd + 0]; j1 = csr[nd + 1]; j2 = csr[nd + 2]; j3 = csr[nd + 3];
                j4 = csr[nd + 4]; j5 = csr[nd + 5]; j6 = csr[nd + 6]; j7 = csr[nd + 7];
            }
            acc.x += ((v0.x + v1.x) + (v2.x + v3.x)) + ((v4.x + v5.x) + (v6.x + v7.x));
            acc.y += ((v0.y + v1.y) + (v2.y + v3.y)) + ((v4.y + v5.y) + (v6.y + v7.y));
            acc.z += ((v0.z + v1.z) + (v2.z + v3.z)) + ((v4.z + v5.z) + (v6.z + v7.z));
            acc.w += ((v0.w + v1.w) + (v2.w + v3.w)) + ((v4.w + v5.w) + (v6.w + v7.w));
            d = nd;
            i0 = j0; i1 = j1; i2 = j2; i3 = j3; i4 = j4; i5 = j5; i6 = j6; i7 = j7;
        }
        // 4-deep tail
        for (; d + 4 <= s1; d += 4) {
            int k0 = csr[d + 0], k1 = csr[d + 1], k2 = csr[d + 2], k3 = csr[d + 3];
            float4 v0 = *(const float4*)(&g1[(size_t)k0 * CHID + c0]);
            float4 v1 = *(const float4*)(&g1[(size_t)k1 * CHID + c0]);
            float4 v2 = *(const float4*)(&g1[(size_t)k2 * CHID + c0]);
            float4 v3 = *(const float4*)(&g1[(size_t)k3 * CHID + c0]);
            acc.x += (v0.x + v1.x) + (v2.x + v3.x);
            acc.y += (v0.y + v1.y) + (v2.y + v3.y);
            acc.z += (v0.z + v1.z) + (v2.z + v3.z);
            acc.w += (v0.w + v1.w) + (v2.w + v3.w);
        }
        for (; d < s1; ++d) {
            int s = csr[d];
            float4 v = *(const float4*)(&g1[(size_t)s * CHID + c0]);
            acc.x += v.x; acc.y += v.y; acc.z += v.z; acc.w += v.w;
        }
        float dv = dinv[node];
        float4 h;
        h.x = acc.x * dv + b.x; h.y = acc.y * dv + b.y;
        h.z = acc.z * dv + b.z; h.w = acc.w * dv + b.w;
        *(float4*)(&h1[(size_t)node * CHID + c0]) = h;
        ps.x += h.x; ps.y += h.y; ps.z += h.z; ps.w += h.w;
        pq.x += h.x * h.x; pq.y += h.y * h.y; pq.z += h.z * h.z; pq.w += h.w * h.w;
    }

    // block-level reduce of BN partial stats, then one atomic per channel
    __shared__ float red[4][CHID];  // 4 KB
    *(float4*)(&red[wave][c0]) = ps;
    __syncthreads();
    {
        int c = tid;  // 0..255
        float v = red[0][c] + red[1][c] + red[2][c] + red[3][c];
        atomicAdd(&stats[c], v);
    }
    __syncthreads();
    *(float4*)(&red[wave][c0]) = pq;
    __syncthreads();
    {
        int c = tid;
        float v = red[0][c] + red[1][c] + red[2][c] + red[3][c];
        atomicAdd(&stats[CHID + c], v);
    }
}

// ---------------------------------------------------------------------------
// BN prep: per-channel affine a*h+bb equivalent to BN(gamma,beta)
// ---------------------------------------------------------------------------
__global__ __launch_bounds__(256) void bnprep_kernel(const float* __restrict__ stats,
                                                     const float* __restrict__ gamma,
                                                     const float* __restrict__ beta,
                                                     float* __restrict__ ab) {
    int c = threadIdx.x;
    float mean = stats[c] * (1.0f / N_NODES);
    float var = stats[CHID + c] * (1.0f / N_NODES) - mean * mean;
    float a = gamma[c] / sqrtf(var + 1e-5f);
    ab[c] = a;
    ab[CHID + c] = beta[c] - mean * a;
}

// ---------------------------------------------------------------------------
// GEMM2: g2[i][o] = dinv[i] * ( relu(a*h1[i,:]+bb) @ W2[:,o] )
// affine+relu applied while staging rows into LDS; 64 rows/block.
// ---------------------------------------------------------------------------
__global__ __launch_bounds__(256) void gemm2_kernel(const float* __restrict__ h1,
                                                    const float* __restrict__ ab,
                                                    const float* __restrict__ W2,
                                                    const float* __restrict__ dinv,
                                                    float* __restrict__ g2) {
    __shared__ float xs[64][CHID];  // 64 KB
    int tid = threadIdx.x;
    int rowBase = blockIdx.x * 64;

    // (tid + j*256) & 63 == tid & 63  ->  affine coeffs are loop-invariant
    int c4 = (tid & 63) * 4;
    float4 a4 = *(const float4*)(&ab[c4]);
    float4 b4 = *(const float4*)(&ab[CHID + c4]);

    const float4* hg = (const float4*)(h1 + (size_t)rowBase * CHID);
#pragma unroll
    for (int j = 0; j < 16; ++j) {
        int idx = tid + j * 256;          // 4096 float4s = 64x256 floats
        float4 v = hg[idx];
        float4 r;
        r.x = fmaxf(v.x * a4.x + b4.x, 0.f);
        r.y = fmaxf(v.y * a4.y + b4.y, 0.f);
        r.z = fmaxf(v.z * a4.z + b4.z, 0.f);
        r.w = fmaxf(v.w * a4.w + b4.w, 0.f);
        ((float4*)(&xs[0][0]))[idx] = r;
    }
    __syncthreads();

    int wave = tid >> 6, lane = tid & 63;
    int o0 = lane * 2;  // 64 lanes x 2 = 128 outputs
    int r0 = wave * 16;

    float2 acc[16];
#pragma unroll
    for (int r = 0; r < 16; ++r) acc[r] = make_float2(0.f, 0.f);

    for (int k = 0; k < CHID; k += 4) {
        float2 w0 = *(const float2*)(&W2[(k + 0) * COUT + o0]);
        float2 w1 = *(const float2*)(&W2[(k + 1) * COUT + o0]);
        float2 w2 = *(const float2*)(&W2[(k + 2) * COUT + o0]);
        float2 w3 = *(const float2*)(&W2[(k + 3) * COUT + o0]);
#pragma unroll
        for (int r = 0; r < 16; ++r) {
            float4 xv = *(const float4*)(&xs[r0 + r][k]);
            acc[r].x += xv.x * w0.x + xv.y * w1.x + xv.z * w2.x + xv.w * w3.x;
            acc[r].y += xv.x * w0.y + xv.y * w1.y + xv.z * w2.y + xv.w * w3.y;
        }
    }

#pragma unroll
    for (int r = 0; r < 16; ++r) {
        int row = rowBase + r0 + r;
        float dv = dinv[row];
        float2 o;
        o.x = acc[r].x * dv; o.y = acc[r].y * dv;
        *(float2*)(&g2[(size_t)row * COUT + o0]) = o;
    }
}

// ---------------------------------------------------------------------------
// AGG2: out[i] = dinv[i]*(sum g2[src] + g2[i]) + b2
// same prefetched 8-deep pipeline as agg1 (512B rows, float2/lane).
// ---------------------------------------------------------------------------
__global__ __launch_bounds__(256, 4) void agg2_kernel(const float* __restrict__ g2,
                                                      const int* __restrict__ offs,
                                                      const int* __restrict__ csr,
                                                      const float* __restrict__ dinv,
                                                      const float* __restrict__ b2,
                                                      float* __restrict__ out) {
    int tid = threadIdx.x, wave = tid >> 6, lane = tid & 63;
    int c0 = lane * 2;
    float2 b = *(const float2*)(&b2[c0]);

    for (int g = blockIdx.x; g < N_NODES / 4; g += gridDim.x) {
        int node = g * 4 + wave;
        int s0 = offs[node], s1 = offs[node + 1];
        float2 acc = *(const float2*)(&g2[(size_t)node * COUT + c0]);  // self loop

        int nb = (s1 - s0) >> 3;
        int d = s0;
        int i0 = 0, i1 = 0, i2 = 0, i3 = 0, i4 = 0, i5 = 0, i6 = 0, i7 = 0;
        if (nb > 0) {
            i0 = csr[d + 0]; i1 = csr[d + 1]; i2 = csr[d + 2]; i3 = csr[d + 3];
            i4 = csr[d + 4]; i5 = csr[d + 5]; i6 = csr[d + 6]; i7 = csr[d + 7];
        }
        for (int t = 0; t < nb; ++t) {
            float2 v0 = *(const float2*)(&g2[(size_t)i0 * COUT + c0]);
            float2 v1 = *(const float2*)(&g2[(size_t)i1 * COUT + c0]);
            float2 v2 = *(const float2*)(&g2[(size_t)i2 * COUT + c0]);
            float2 v3 = *(const float2*)(&g2[(size_t)i3 * COUT + c0]);
            float2 v4 = *(const float2*)(&g2[(size_t)i4 * COUT + c0]);
            float2 v5 = *(const float2*)(&g2[(size_t)i5 * COUT + c0]);
            float2 v6 = *(const float2*)(&g2[(size_t)i6 * COUT + c0]);
            float2 v7 = *(const float2*)(&g2[(size_t)i7 * COUT + c0]);
            int nd = d + 8;
            int j0 = 0, j1 = 0, j2 = 0, j3 = 0, j4 = 0, j5 = 0, j6 = 0, j7 = 0;
            if (t + 1 < nb) {
                j0 = csr[nd + 0]; j1 = csr[nd + 1]; j2 = csr[nd + 2]; j3 = csr[nd + 3];
                j4 = csr[nd + 4]; j5 = csr[nd + 5]; j6 = csr[nd + 6]; j7 = csr[nd + 7];
            }
            acc.x += ((v0.x + v1.x) + (v2.x + v3.x)) + ((v4.x + v5.x) + (v6.x + v7.x));
            acc.y += ((v0.y + v1.y) + (v2.y + v3.y)) + ((v4.y + v5.y) + (v6.y + v7.y));
            d = nd;
            i0 = j0; i1 = j1; i2 = j2; i3 = j3; i4 = j4; i5 = j5; i6 = j6; i7 = j7;
        }
        for (; d + 4 <= s1; d += 4) {
            int k0 = csr[d + 0], k1 = csr[d + 1], k2 = csr[d + 2], k3 = csr[d + 3];
            float2 v0 = *(const float2*)(&g2[(size_t)k0 * COUT + c0]);
            float2 v1 = *(const float2*)(&g2[(size_t)k1 * COUT + c0]);
            float2 v2 = *(const float2*)(&g2[(size_t)k2 * COUT + c0]);
            float2 v3 = *(const float2*)(&g2[(size_t)k3 * COUT + c0]);
            acc.x += (v0.x + v1.x) + (v2.x + v3.x);
            acc.y += (v0.y + v1.y) + (v2.y + v3.y);
        }
        for (; d < s1; ++d) {
            int s = csr[d];
            float2 v = *(const float2*)(&g2[(size_t)s * COUT + c0]);
            acc.x += v.x; acc.y += v.y;
        }
        float dv = dinv[node];
        float2 o;
        o.x = acc.x * dv + b.x;
        o.y = acc.y * dv + b.y;
        *(float2*)(&out[(size_t)node * COUT + c0]) = o;
    }
}

// ---------------------------------------------------------------------------
extern "C" void kernel_launch(void* const* d_in, const int* in_sizes, int n_in,
                              void* d_out, int out_size, void* d_ws, size_t ws_size,
                              hipStream_t stream) {
    const float* x     = (const float*)d_in[0];
    const int*   ei    = (const int*)d_in[1];
    const float* W1    = (const float*)d_in[2];
    const float* b1    = (const float*)d_in[3];
    const float* gamma = (const float*)d_in[4];
    const float* beta  = (const float*)d_in[5];
    const float* W2    = (const float*)d_in[6];
    const float* b2    = (const float*)d_in[7];
    float* out = (float*)d_out;

    const int* srcv = ei;            // edge_index[0]
    const int* dstv = ei + E_EDGES;  // edge_index[1]

    // workspace layout (g2 aliases g1: g1 dead after agg1)
    char* ws = (char*)d_ws;
    size_t off = 0;
    auto alloc = [&](size_t bytes) -> void* {
        void* p = ws + off;
        off += (bytes + 255) & ~(size_t)255;
        return p;
    };
    int*   deg    = (int*)alloc((size_t)N_NODES * 4);
    int*   offs   = (int*)alloc((size_t)(N_NODES + 1) * 4);
    int*   cursor = (int*)alloc((size_t)N_NODES * 4);
    float* dinv   = (float*)alloc((size_t)N_NODES * 4);
    int*   csr    = (int*)alloc((size_t)E_EDGES * 4);
    float* g1     = (float*)alloc((size_t)N_NODES * CHID * 4);  // also g2
    float* h1     = (float*)alloc((size_t)N_NODES * CHID * 4);
    float* stats  = (float*)alloc(2 * CHID * 4);
    float* ab     = (float*)alloc(2 * CHID * 4);
    float* g2     = g1;

    hipMemsetAsync(deg, 0, (size_t)N_NODES * 4, stream);
    hipMemsetAsync(stats, 0, 2 * CHID * 4, stream);

    deg_kernel<<<E_EDGES / 256, 256, 0, stream>>>(dstv, deg);
    scan_kernel<<<1, 1024, 0, stream>>>(deg, offs, cursor, dinv);
    fill_kernel<<<E_EDGES / 256, 256, 0, stream>>>(srcv, dstv, cursor, csr);

    gemm1_kernel<<<N_NODES / 64, 256, 0, stream>>>(x, W1, dinv, g1);
    agg1_kernel<<<2048, 256, 0, stream>>>(g1, offs, csr, dinv, b1, h1, stats);
    bnprep_kernel<<<1, 256, 0, stream>>>(stats, gamma, beta, ab);
    gemm2_kernel<<<N_NODES / 64, 256, 0, stream>>>(h1, ab, W2, dinv, g2);
    agg2_kernel<<<2048, 256, 0, stream>>>(g2, offs, csr, dinv, b2, out);
}

// Round 6
// 433.443 us; speedup vs baseline: 1.2336x; 1.2334x over previous
//
#include <hip/hip_runtime.h>
#include <hip/hip_bf16.h>
#include <math.h>

#define N_NODES 32768
#define E_EDGES 1048576
#define CIN 128
#define CHID 256
#define COUT 128

// bf16 <-> f32 helpers: store gather tables (g1,g2) as bf16 to halve the
// random-gather traffic (R4 evidence: agg fabric path saturates ~3.5 TB/s,
// BW/request-bound, so bytes are the lever). Accumulate in f32.
__device__ inline float bf2f(unsigned short u) {
    union { unsigned int i; float f; } c;
    c.i = ((unsigned int)u) << 16;
    return c.f;
}
__device__ inline unsigned short f2bf(float f) {
    __hip_bfloat16 h = __float2bfloat16(f);  // RNE
    return *reinterpret_cast<unsigned short*>(&h);
}

// ---------------------------------------------------------------------------
// CSR build: deg count -> exclusive scan (+dinv) -> fill
// ---------------------------------------------------------------------------
__global__ __launch_bounds__(256) void deg_kernel(const int* __restrict__ dst,
                                                  int* __restrict__ deg) {
    int e = blockIdx.x * blockDim.x + threadIdx.x;
    if (e < E_EDGES) atomicAdd(&deg[dst[e]], 1);
}

__global__ __launch_bounds__(1024) void scan_kernel(const int* __restrict__ deg,
                                                    int* __restrict__ offs,
                                                    int* __restrict__ cursor,
                                                    float* __restrict__ dinv) {
    __shared__ int s[1024];
    int t = threadIdx.x;
    int base = t * 32;  // 1024 threads x 32 = 32768
    int ts = 0;
#pragma unroll
    for (int j = 0; j < 32; ++j) ts += deg[base + j];
    s[t] = ts;
    __syncthreads();
    // Hillis-Steele inclusive scan over 1024 thread-sums (double-barrier form)
    for (int off = 1; off < 1024; off <<= 1) {
        int v = (t >= off) ? s[t - off] : 0;
        __syncthreads();
        s[t] += v;
        __syncthreads();
    }
    int run = s[t] - ts;  // exclusive prefix for this chunk
    for (int j = 0; j < 32; ++j) {
        int idx = base + j;
        int d = deg[idx];
        offs[idx] = run;
        cursor[idx] = run;
        // reference deg includes the self-loop: indeg + 1 (always >= 1)
        dinv[idx] = 1.0f / sqrtf((float)(d + 1));
        run += d;
    }
    if (t == 1023) offs[N_NODES] = s[1023];
}

__global__ __launch_bounds__(256) void fill_kernel(const int* __restrict__ src,
                                                   const int* __restrict__ dst,
                                                   int* __restrict__ cursor,
                                                   int* __restrict__ csr) {
    int e = blockIdx.x * blockDim.x + threadIdx.x;
    if (e < E_EDGES) {
        int d = dst[e];
        int pos = atomicAdd(&cursor[d], 1);
        csr[pos] = src[e];
    }
}

// ---------------------------------------------------------------------------
// GEMM1: g1[i][c] = bf16( (x[i,:] @ W1[:,c]) * dinv[i] )
// 64 rows/block (16 rows/wave) to amortize W1 L2 traffic; xs broadcast-read.
// ---------------------------------------------------------------------------
__global__ __launch_bounds__(256) void gemm1_kernel(const float* __restrict__ x,
                                                    const float* __restrict__ W1,
                                                    const float* __restrict__ dinv,
                                                    unsigned short* __restrict__ g1) {
    __shared__ float xs[64][CIN];  // 32 KB
    int tid = threadIdx.x;
    int rowBase = blockIdx.x * 64;

    // cooperative load of 64x128 f32 tile (contiguous 32 KB)
    const float4* xg = (const float4*)(x + (size_t)rowBase * CIN);
    float4* xsv = (float4*)(&xs[0][0]);
#pragma unroll
    for (int j = 0; j < 8; ++j) xsv[tid + j * 256] = xg[tid + j * 256];
    __syncthreads();

    int wave = tid >> 6, lane = tid & 63;
    int c0 = lane * 4;   // 64 lanes x 4 = 256 output channels
    int r0 = wave * 16;

    float4 acc[16];
#pragma unroll
    for (int r = 0; r < 16; ++r) acc[r] = make_float4(0.f, 0.f, 0.f, 0.f);

    for (int k = 0; k < CIN; k += 4) {
        float4 w0 = *(const float4*)(&W1[(k + 0) * CHID + c0]);
        float4 w1 = *(const float4*)(&W1[(k + 1) * CHID + c0]);
        float4 w2 = *(const float4*)(&W1[(k + 2) * CHID + c0]);
        float4 w3 = *(const float4*)(&W1[(k + 3) * CHID + c0]);
#pragma unroll
        for (int r = 0; r < 16; ++r) {
            float4 xv = *(const float4*)(&xs[r0 + r][k]);
            acc[r].x += xv.x * w0.x + xv.y * w1.x + xv.z * w2.x + xv.w * w3.x;
            acc[r].y += xv.x * w0.y + xv.y * w1.y + xv.z * w2.y + xv.w * w3.y;
            acc[r].z += xv.x * w0.z + xv.y * w1.z + xv.z * w2.z + xv.w * w3.z;
            acc[r].w += xv.x * w0.w + xv.y * w1.w + xv.z * w2.w + xv.w * w3.w;
        }
    }

#pragma unroll
    for (int r = 0; r < 16; ++r) {
        int row = rowBase + r0 + r;
        float dv = dinv[row];
        ushort4 o;
        o.x = f2bf(acc[r].x * dv); o.y = f2bf(acc[r].y * dv);
        o.z = f2bf(acc[r].z * dv); o.w = f2bf(acc[r].w * dv);
        *(ushort4*)(&g1[(size_t)row * CHID + c0]) = o;  // 8B store
    }
}

// ---------------------------------------------------------------------------
// AGG1: h1[i] = dinv[i]*(sum_{e:dst=i} g1[src] + g1[i]) + b1
// one wave per node; lane owns 4 channels (ushort4 = 8B/lane, 512B/row).
// 8-deep gather batches with next batch's csr indices prefetched; f32 accum.
// ---------------------------------------------------------------------------
__global__ __launch_bounds__(256) void agg1_kernel(const unsigned short* __restrict__ g1,
                                                   const int* __restrict__ offs,
                                                   const int* __restrict__ csr,
                                                   const float* __restrict__ dinv,
                                                   const float* __restrict__ b1,
                                                   float* __restrict__ h1,
                                                   float* __restrict__ stats) {
    int tid = threadIdx.x, wave = tid >> 6, lane = tid & 63;
    int c0 = lane * 4;
    float4 b = *(const float4*)(&b1[c0]);
    float4 ps = make_float4(0.f, 0.f, 0.f, 0.f);
    float4 pq = make_float4(0.f, 0.f, 0.f, 0.f);

    for (int g = blockIdx.x; g < N_NODES / 4; g += gridDim.x) {
        int node = g * 4 + wave;
        int s0 = offs[node], s1 = offs[node + 1];
        // self loop contribution
        ushort4 sv = *(const ushort4*)(&g1[(size_t)node * CHID + c0]);
        float4 acc;
        acc.x = bf2f(sv.x); acc.y = bf2f(sv.y); acc.z = bf2f(sv.z); acc.w = bf2f(sv.w);

        int nb = (s1 - s0) >> 3;  // full 8-batches
        int d = s0;
        int i0 = 0, i1 = 0, i2 = 0, i3 = 0, i4 = 0, i5 = 0, i6 = 0, i7 = 0;
        if (nb > 0) {
            i0 = csr[d + 0]; i1 = csr[d + 1]; i2 = csr[d + 2]; i3 = csr[d + 3];
            i4 = csr[d + 4]; i5 = csr[d + 5]; i6 = csr[d + 6]; i7 = csr[d + 7];
        }
        for (int t = 0; t < nb; ++t) {
            // 8 independent 512B row gathers (8B/lane each) in flight
            ushort4 v0 = *(const ushort4*)(&g1[(size_t)i0 * CHID + c0]);
            ushort4 v1 = *(const ushort4*)(&g1[(size_t)i1 * CHID + c0]);
            ushort4 v2 = *(const ushort4*)(&g1[(size_t)i2 * CHID + c0]);
            ushort4 v3 = *(const ushort4*)(&g1[(size_t)i3 * CHID + c0]);
            ushort4 v4 = *(const ushort4*)(&g1[(size_t)i4 * CHID + c0]);
            ushort4 v5 = *(const ushort4*)(&g1[(size_t)i5 * CHID + c0]);
            ushort4 v6 = *(const ushort4*)(&g1[(size_t)i6 * CHID + c0]);
            ushort4 v7 = *(const ushort4*)(&g1[(size_t)i7 * CHID + c0]);
            // prefetch next batch's indices while gathers are in flight
            int nd = d + 8;
            int j0 = 0, j1 = 0, j2 = 0, j3 = 0, j4 = 0, j5 = 0, j6 = 0, j7 = 0;
            if (t + 1 < nb) {
                j0 = csr[nd + 0]; j1 = csr[nd + 1]; j2 = csr[nd + 2]; j3 = csr[nd + 3];
                j4 = csr[nd + 4]; j5 = csr[nd + 5]; j6 = csr[nd + 6]; j7 = csr[nd + 7];
            }
            acc.x += ((bf2f(v0.x) + bf2f(v1.x)) + (bf2f(v2.x) + bf2f(v3.x))) +
                     ((bf2f(v4.x) + bf2f(v5.x)) + (bf2f(v6.x) + bf2f(v7.x)));
            acc.y += ((bf2f(v0.y) + bf2f(v1.y)) + (bf2f(v2.y) + bf2f(v3.y))) +
                     ((bf2f(v4.y) + bf2f(v5.y)) + (bf2f(v6.y) + bf2f(v7.y)));
            acc.z += ((bf2f(v0.z) + bf2f(v1.z)) + (bf2f(v2.z) + bf2f(v3.z))) +
                     ((bf2f(v4.z) + bf2f(v5.z)) + (bf2f(v6.z) + bf2f(v7.z)));
            acc.w += ((bf2f(v0.w) + bf2f(v1.w)) + (bf2f(v2.w) + bf2f(v3.w))) +
                     ((bf2f(v4.w) + bf2f(v5.w)) + (bf2f(v6.w) + bf2f(v7.w)));
            d = nd;
            i0 = j0; i1 = j1; i2 = j2; i3 = j3; i4 = j4; i5 = j5; i6 = j6; i7 = j7;
        }
        // 4-deep tail
        for (; d + 4 <= s1; d += 4) {
            int k0 = csr[d + 0], k1 = csr[d + 1], k2 = csr[d + 2], k3 = csr[d + 3];
            ushort4 v0 = *(const ushort4*)(&g1[(size_t)k0 * CHID + c0]);
            ushort4 v1 = *(const ushort4*)(&g1[(size_t)k1 * CHID + c0]);
            ushort4 v2 = *(const ushort4*)(&g1[(size_t)k2 * CHID + c0]);
            ushort4 v3 = *(const ushort4*)(&g1[(size_t)k3 * CHID + c0]);
            acc.x += (bf2f(v0.x) + bf2f(v1.x)) + (bf2f(v2.x) + bf2f(v3.x));
            acc.y += (bf2f(v0.y) + bf2f(v1.y)) + (bf2f(v2.y) + bf2f(v3.y));
            acc.z += (bf2f(v0.z) + bf2f(v1.z)) + (bf2f(v2.z) + bf2f(v3.z));
            acc.w += (bf2f(v0.w) + bf2f(v1.w)) + (bf2f(v2.w) + bf2f(v3.w));
        }
        for (; d < s1; ++d) {
            int s = csr[d];
            ushort4 v = *(const ushort4*)(&g1[(size_t)s * CHID + c0]);
            acc.x += bf2f(v.x); acc.y += bf2f(v.y);
            acc.z += bf2f(v.z); acc.w += bf2f(v.w);
        }
        float dv = dinv[node];
        float4 h;
        h.x = acc.x * dv + b.x; h.y = acc.y * dv + b.y;
        h.z = acc.z * dv + b.z; h.w = acc.w * dv + b.w;
        *(float4*)(&h1[(size_t)node * CHID + c0]) = h;
        ps.x += h.x; ps.y += h.y; ps.z += h.z; ps.w += h.w;
        pq.x += h.x * h.x; pq.y += h.y * h.y; pq.z += h.z * h.z; pq.w += h.w * h.w;
    }

    // block-level reduce of BN partial stats, then one atomic per channel
    __shared__ float red[4][CHID];  // 4 KB
    *(float4*)(&red[wave][c0]) = ps;
    __syncthreads();
    {
        int c = tid;  // 0..255
        float v = red[0][c] + red[1][c] + red[2][c] + red[3][c];
        atomicAdd(&stats[c], v);
    }
    __syncthreads();
    *(float4*)(&red[wave][c0]) = pq;
    __syncthreads();
    {
        int c = tid;
        float v = red[0][c] + red[1][c] + red[2][c] + red[3][c];
        atomicAdd(&stats[CHID + c], v);
    }
}

// ---------------------------------------------------------------------------
// BN prep: per-channel affine a*h+bb equivalent to BN(gamma,beta)
// ---------------------------------------------------------------------------
__global__ __launch_bounds__(256) void bnprep_kernel(const float* __restrict__ stats,
                                                     const float* __restrict__ gamma,
                                                     const float* __restrict__ beta,
                                                     float* __restrict__ ab) {
    int c = threadIdx.x;
    float mean = stats[c] * (1.0f / N_NODES);
    float var = stats[CHID + c] * (1.0f / N_NODES) - mean * mean;
    float a = gamma[c] / sqrtf(var + 1e-5f);
    ab[c] = a;
    ab[CHID + c] = beta[c] - mean * a;
}

// ---------------------------------------------------------------------------
// GEMM2: g2[i][o] = bf16( dinv[i] * ( relu(a*h1[i,:]+bb) @ W2[:,o] ) )
// affine+relu applied while staging rows into LDS; 64 rows/block.
// ---------------------------------------------------------------------------
__global__ __launch_bounds__(256) void gemm2_kernel(const float* __restrict__ h1,
                                                    const float* __restrict__ ab,
                                                    const float* __restrict__ W2,
                                                    const float* __restrict__ dinv,
                                                    unsigned short* __restrict__ g2) {
    __shared__ float xs[64][CHID];  // 64 KB
    int tid = threadIdx.x;
    int rowBase = blockIdx.x * 64;

    // (tid + j*256) & 63 == tid & 63  ->  affine coeffs are loop-invariant
    int c4 = (tid & 63) * 4;
    float4 a4 = *(const float4*)(&ab[c4]);
    float4 b4 = *(const float4*)(&ab[CHID + c4]);

    const float4* hg = (const float4*)(h1 + (size_t)rowBase * CHID);
#pragma unroll
    for (int j = 0; j < 16; ++j) {
        int idx = tid + j * 256;          // 4096 float4s = 64x256 floats
        float4 v = hg[idx];
        float4 r;
        r.x = fmaxf(v.x * a4.x + b4.x, 0.f);
        r.y = fmaxf(v.y * a4.y + b4.y, 0.f);
        r.z = fmaxf(v.z * a4.z + b4.z, 0.f);
        r.w = fmaxf(v.w * a4.w + b4.w, 0.f);
        ((float4*)(&xs[0][0]))[idx] = r;
    }
    __syncthreads();

    int wave = tid >> 6, lane = tid & 63;
    int o0 = lane * 2;  // 64 lanes x 2 = 128 outputs
    int r0 = wave * 16;

    float2 acc[16];
#pragma unroll
    for (int r = 0; r < 16; ++r) acc[r] = make_float2(0.f, 0.f);

    for (int k = 0; k < CHID; k += 4) {
        float2 w0 = *(const float2*)(&W2[(k + 0) * COUT + o0]);
        float2 w1 = *(const float2*)(&W2[(k + 1) * COUT + o0]);
        float2 w2 = *(const float2*)(&W2[(k + 2) * COUT + o0]);
        float2 w3 = *(const float2*)(&W2[(k + 3) * COUT + o0]);
#pragma unroll
        for (int r = 0; r < 16; ++r) {
            float4 xv = *(const float4*)(&xs[r0 + r][k]);
            acc[r].x += xv.x * w0.x + xv.y * w1.x + xv.z * w2.x + xv.w * w3.x;
            acc[r].y += xv.x * w0.y + xv.y * w1.y + xv.z * w2.y + xv.w * w3.y;
        }
    }

#pragma unroll
    for (int r = 0; r < 16; ++r) {
        int row = rowBase + r0 + r;
        float dv = dinv[row];
        ushort2 o;
        o.x = f2bf(acc[r].x * dv);
        o.y = f2bf(acc[r].y * dv);
        *(ushort2*)(&g2[(size_t)row * COUT + o0]) = o;  // 4B store
    }
}

// ---------------------------------------------------------------------------
// AGG2: out[i] = dinv[i]*(sum g2[src] + g2[i]) + b2
// same prefetched 8-deep pipeline as agg1 (256B rows, ushort2 = 4B/lane).
// ---------------------------------------------------------------------------
__global__ __launch_bounds__(256) void agg2_kernel(const unsigned short* __restrict__ g2,
                                                   const int* __restrict__ offs,
                                                   const int* __restrict__ csr,
                                                   const float* __restrict__ dinv,
                                                   const float* __restrict__ b2,
                                                   float* __restrict__ out) {
    int tid = threadIdx.x, wave = tid >> 6, lane = tid & 63;
    int c0 = lane * 2;
    float2 b = *(const float2*)(&b2[c0]);

    for (int g = blockIdx.x; g < N_NODES / 4; g += gridDim.x) {
        int node = g * 4 + wave;
        int s0 = offs[node], s1 = offs[node + 1];
        ushort2 sv = *(const ushort2*)(&g2[(size_t)node * COUT + c0]);  // self loop
        float2 acc;
        acc.x = bf2f(sv.x); acc.y = bf2f(sv.y);

        int nb = (s1 - s0) >> 3;
        int d = s0;
        int i0 = 0, i1 = 0, i2 = 0, i3 = 0, i4 = 0, i5 = 0, i6 = 0, i7 = 0;
        if (nb > 0) {
            i0 = csr[d + 0]; i1 = csr[d + 1]; i2 = csr[d + 2]; i3 = csr[d + 3];
            i4 = csr[d + 4]; i5 = csr[d + 5]; i6 = csr[d + 6]; i7 = csr[d + 7];
        }
        for (int t = 0; t < nb; ++t) {
            ushort2 v0 = *(const ushort2*)(&g2[(size_t)i0 * COUT + c0]);
            ushort2 v1 = *(const ushort2*)(&g2[(size_t)i1 * COUT + c0]);
            ushort2 v2 = *(const ushort2*)(&g2[(size_t)i2 * COUT + c0]);
            ushort2 v3 = *(const ushort2*)(&g2[(size_t)i3 * COUT + c0]);
            ushort2 v4 = *(const ushort2*)(&g2[(size_t)i4 * COUT + c0]);
            ushort2 v5 = *(const ushort2*)(&g2[(size_t)i5 * COUT + c0]);
            ushort2 v6 = *(const ushort2*)(&g2[(size_t)i6 * COUT + c0]);
            ushort2 v7 = *(const ushort2*)(&g2[(size_t)i7 * COUT + c0]);
            int nd = d + 8;
            int j0 = 0, j1 = 0, j2 = 0, j3 = 0, j4 = 0, j5 = 0, j6 = 0, j7 = 0;
            if (t + 1 < nb) {
                j0 = csr[nd + 0]; j1 = csr[nd + 1]; j2 = csr[nd + 2]; j3 = csr[nd + 3];
                j4 = csr[nd + 4]; j5 = csr[nd + 5]; j6 = csr[nd + 6]; j7 = csr[nd + 7];
            }
            acc.x += ((bf2f(v0.x) + bf2f(v1.x)) + (bf2f(v2.x) + bf2f(v3.x))) +
                     ((bf2f(v4.x) + bf2f(v5.x)) + (bf2f(v6.x) + bf2f(v7.x)));
            acc.y += ((bf2f(v0.y) + bf2f(v1.y)) + (bf2f(v2.y) + bf2f(v3.y))) +
                     ((bf2f(v4.y) + bf2f(v5.y)) + (bf2f(v6.y) + bf2f(v7.y)));
            d = nd;
            i0 = j0; i1 = j1; i2 = j2; i3 = j3; i4 = j4; i5 = j5; i6 = j6; i7 = j7;
        }
        for (; d + 4 <= s1; d += 4) {
            int k0 = csr[d + 0], k1 = csr[d + 1], k2 = csr[d + 2], k3 = csr[d + 3];
            ushort2 v0 = *(const ushort2*)(&g2[(size_t)k0 * COUT + c0]);
            ushort2 v1 = *(const ushort2*)(&g2[(size_t)k1 * COUT + c0]);
            ushort2 v2 = *(const ushort2*)(&g2[(size_t)k2 * COUT + c0]);
            ushort2 v3 = *(const ushort2*)(&g2[(size_t)k3 * COUT + c0]);
            acc.x += (bf2f(v0.x) + bf2f(v1.x)) + (bf2f(v2.x) + bf2f(v3.x));
            acc.y += (bf2f(v0.y) + bf2f(v1.y)) + (bf2f(v2.y) + bf2f(v3.y));
        }
        for (; d < s1; ++d) {
            int s = csr[d];
            ushort2 v = *(const ushort2*)(&g2[(size_t)s * COUT + c0]);
            acc.x += bf2f(v.x); acc.y += bf2f(v.y);
        }
        float dv = dinv[node];
        float2 o;
        o.x = acc.x * dv + b.x;
        o.y = acc.y * dv + b.y;
        *(float2*)(&out[(size_t)node * COUT + c0]) = o;
    }
}

// ---------------------------------------------------------------------------
extern "C" void kernel_launch(void* const* d_in, const int* in_sizes, int n_in,
                              void* d_out, int out_size, void* d_ws, size_t ws_size,
                              hipStream_t stream) {
    const float* x     = (const float*)d_in[0];
    const int*   ei    = (const int*)d_in[1];
    const float* W1    = (const float*)d_in[2];
    const float* b1    = (const float*)d_in[3];
    const float* gamma = (const float*)d_in[4];
    const float* beta  = (const float*)d_in[5];
    const float* W2    = (const float*)d_in[6];
    const float* b2    = (const float*)d_in[7];
    float* out = (float*)d_out;

    const int* srcv = ei;            // edge_index[0]
    const int* dstv = ei + E_EDGES;  // edge_index[1]

    // workspace layout (g2 aliases g1: g1 dead after agg1)
    char* ws = (char*)d_ws;
    size_t off = 0;
    auto alloc = [&](size_t bytes) -> void* {
        void* p = ws + off;
        off += (bytes + 255) & ~(size_t)255;
        return p;
    };
    int*   deg    = (int*)alloc((size_t)N_NODES * 4);
    int*   offs   = (int*)alloc((size_t)(N_NODES + 1) * 4);
    int*   cursor = (int*)alloc((size_t)N_NODES * 4);
    float* dinv   = (float*)alloc((size_t)N_NODES * 4);
    int*   csr    = (int*)alloc((size_t)E_EDGES * 4);
    unsigned short* g1 = (unsigned short*)alloc((size_t)N_NODES * CHID * 2);  // bf16, also g2
    float* h1     = (float*)alloc((size_t)N_NODES * CHID * 4);
    float* stats  = (float*)alloc(2 * CHID * 4);
    float* ab     = (float*)alloc(2 * CHID * 4);
    unsigned short* g2 = g1;

    hipMemsetAsync(deg, 0, (size_t)N_NODES * 4, stream);
    hipMemsetAsync(stats, 0, 2 * CHID * 4, stream);

    deg_kernel<<<E_EDGES / 256, 256, 0, stream>>>(dstv, deg);
    scan_kernel<<<1, 1024, 0, stream>>>(deg, offs, cursor, dinv);
    fill_kernel<<<E_EDGES / 256, 256, 0, stream>>>(srcv, dstv, cursor, csr);

    gemm1_kernel<<<N_NODES / 64, 256, 0, stream>>>(x, W1, dinv, g1);
    agg1_kernel<<<2048, 256, 0, stream>>>(g1, offs, csr, dinv, b1, h1, stats);
    bnprep_kernel<<<1, 256, 0, stream>>>(stats, gamma, beta, ab);
    gemm2_kernel<<<N_NODES / 64, 256, 0, stream>>>(h1, ab, W2, dinv, g2);
    agg2_kernel<<<2048, 256, 0, stream>>>(g2, offs, csr, dinv, b2, out);
}

// Round 9
// 398.800 us; speedup vs baseline: 1.3407x; 1.0869x over previous
//
#include <hip/hip_runtime.h>
#include <hip/hip_bf16.h>
#include <math.h>

#define N_NODES 32768
#define E_EDGES 1048576
#define CIN 128
#define CHID 256
#define COUT 128

// bf16 <-> f32 helpers. Gather tables (x~, g2) stored bf16: R6 evidence says
// the agg path is bytes+requests bound, so smaller rows are the lever.
__device__ inline float bf2f(unsigned short u) {
    union { unsigned int i; float f; } c;
    c.i = ((unsigned int)u) << 16;
    return c.f;
}
__device__ inline unsigned short f2bf(float f) {
    __hip_bfloat16 h = __float2bfloat16(f);  // RNE
    return *reinterpret_cast<unsigned short*>(&h);
}

// ---------------------------------------------------------------------------
// CSR build: deg count -> exclusive scan (+dinv) -> fill
// ---------------------------------------------------------------------------
__global__ __launch_bounds__(256) void deg_kernel(const int* __restrict__ dst,
                                                  int* __restrict__ deg) {
    int e = blockIdx.x * blockDim.x + threadIdx.x;
    if (e < E_EDGES) atomicAdd(&deg[dst[e]], 1);
}

__global__ __launch_bounds__(1024) void scan_kernel(const int* __restrict__ deg,
                                                    int* __restrict__ offs,
                                                    int* __restrict__ cursor,
                                                    float* __restrict__ dinv) {
    __shared__ int s[1024];
    int t = threadIdx.x;
    int base = t * 32;  // 1024 threads x 32 = 32768
    int ts = 0;
#pragma unroll
    for (int j = 0; j < 32; ++j) ts += deg[base + j];
    s[t] = ts;
    __syncthreads();
    // Hillis-Steele inclusive scan over 1024 thread-sums (double-barrier form)
    for (int off = 1; off < 1024; off <<= 1) {
        int v = (t >= off) ? s[t - off] : 0;
        __syncthreads();
        s[t] += v;
        __syncthreads();
    }
    int run = s[t] - ts;  // exclusive prefix for this chunk
    for (int j = 0; j < 32; ++j) {
        int idx = base + j;
        int d = deg[idx];
        offs[idx] = run;
        cursor[idx] = run;
        // reference deg includes the self-loop: indeg + 1 (always >= 1)
        dinv[idx] = 1.0f / sqrtf((float)(d + 1));
        run += d;
    }
    if (t == 1023) offs[N_NODES] = s[1023];
}

__global__ __launch_bounds__(256) void fill_kernel(const int* __restrict__ src,
                                                   const int* __restrict__ dst,
                                                   int* __restrict__ cursor,
                                                   int* __restrict__ csr) {
    int e = blockIdx.x * blockDim.x + threadIdx.x;
    if (e < E_EDGES) {
        int d = dst[e];
        int pos = atomicAdd(&cursor[d], 1);
        csr[pos] = src[e];
    }
}

// ---------------------------------------------------------------------------
// QUANTX: xq[i][c] = bf16( x[i][c] * dinv[i] )   (256B rows for the gather)
// ---------------------------------------------------------------------------
__global__ __launch_bounds__(256) void quantx_kernel(const float* __restrict__ x,
                                                     const float* __restrict__ dinv,
                                                     unsigned short* __restrict__ xq) {
    int idx = blockIdx.x * 256 + threadIdx.x;  // float4 index; N*CIN/4 total
    int row = idx >> 5;                        // 32 float4s per 128-ch row
    float dv = dinv[row];
    float4 v = ((const float4*)x)[idx];
    ushort4 o;
    o.x = f2bf(v.x * dv); o.y = f2bf(v.y * dv);
    o.z = f2bf(v.z * dv); o.w = f2bf(v.w * dv);
    ((ushort4*)xq)[idx] = o;
}

// ---------------------------------------------------------------------------
// AGGX: u[i] = dinv[i]*(sum_{e:dst=i} xq[src] + xq[i])      (layer-1 agg in
// the 128-dim INPUT space: agg commutes with @W1, so gather 256B rows not
// 512B). One wave per node; lane owns 2 channels (ushort2 = 4B/lane);
// 8-deep gather pipeline with next-batch index prefetch; f32 accum.
// ---------------------------------------------------------------------------
__global__ __launch_bounds__(256) void aggx_kernel(const unsigned short* __restrict__ xq,
                                                   const int* __restrict__ offs,
                                                   const int* __restrict__ csr,
                                                   const float* __restrict__ dinv,
                                                   float* __restrict__ u) {
    int tid = threadIdx.x, wave = tid >> 6, lane = tid & 63;
    int c0 = lane * 2;

    for (int g = blockIdx.x; g < N_NODES / 4; g += gridDim.x) {
        int node = g * 4 + wave;
        int s0 = offs[node], s1 = offs[node + 1];
        ushort2 sv = *(const ushort2*)(&xq[(size_t)node * CIN + c0]);  // self loop
        float2 acc;
        acc.x = bf2f(sv.x); acc.y = bf2f(sv.y);

        int nb = (s1 - s0) >> 3;
        int d = s0;
        int i0 = 0, i1 = 0, i2 = 0, i3 = 0, i4 = 0, i5 = 0, i6 = 0, i7 = 0;
        if (nb > 0) {
            i0 = csr[d + 0]; i1 = csr[d + 1]; i2 = csr[d + 2]; i3 = csr[d + 3];
            i4 = csr[d + 4]; i5 = csr[d + 5]; i6 = csr[d + 6]; i7 = csr[d + 7];
        }
        for (int t = 0; t < nb; ++t) {
            ushort2 v0 = *(const ushort2*)(&xq[(size_t)i0 * CIN + c0]);
            ushort2 v1 = *(const ushort2*)(&xq[(size_t)i1 * CIN + c0]);
            ushort2 v2 = *(const ushort2*)(&xq[(size_t)i2 * CIN + c0]);
            ushort2 v3 = *(const ushort2*)(&xq[(size_t)i3 * CIN + c0]);
            ushort2 v4 = *(const ushort2*)(&xq[(size_t)i4 * CIN + c0]);
            ushort2 v5 = *(const ushort2*)(&xq[(size_t)i5 * CIN + c0]);
            ushort2 v6 = *(const ushort2*)(&xq[(size_t)i6 * CIN + c0]);
            ushort2 v7 = *(const ushort2*)(&xq[(size_t)i7 * CIN + c0]);
            int nd = d + 8;
            int j0 = 0, j1 = 0, j2 = 0, j3 = 0, j4 = 0, j5 = 0, j6 = 0, j7 = 0;
            if (t + 1 < nb) {
                j0 = csr[nd + 0]; j1 = csr[nd + 1]; j2 = csr[nd + 2]; j3 = csr[nd + 3];
                j4 = csr[nd + 4]; j5 = csr[nd + 5]; j6 = csr[nd + 6]; j7 = csr[nd + 7];
            }
            acc.x += ((bf2f(v0.x) + bf2f(v1.x)) + (bf2f(v2.x) + bf2f(v3.x))) +
                     ((bf2f(v4.x) + bf2f(v5.x)) + (bf2f(v6.x) + bf2f(v7.x)));
            acc.y += ((bf2f(v0.y) + bf2f(v1.y)) + (bf2f(v2.y) + bf2f(v3.y))) +
                     ((bf2f(v4.y) + bf2f(v5.y)) + (bf2f(v6.y) + bf2f(v7.y)));
            d = nd;
            i0 = j0; i1 = j1; i2 = j2; i3 = j3; i4 = j4; i5 = j5; i6 = j6; i7 = j7;
        }
        for (; d + 4 <= s1; d += 4) {
            int k0 = csr[d + 0], k1 = csr[d + 1], k2 = csr[d + 2], k3 = csr[d + 3];
            ushort2 v0 = *(const ushort2*)(&xq[(size_t)k0 * CIN + c0]);
            ushort2 v1 = *(const ushort2*)(&xq[(size_t)k1 * CIN + c0]);
            ushort2 v2 = *(const ushort2*)(&xq[(size_t)k2 * CIN + c0]);
            ushort2 v3 = *(const ushort2*)(&xq[(size_t)k3 * CIN + c0]);
            acc.x += (bf2f(v0.x) + bf2f(v1.x)) + (bf2f(v2.x) + bf2f(v3.x));
            acc.y += (bf2f(v0.y) + bf2f(v1.y)) + (bf2f(v2.y) + bf2f(v3.y));
        }
        for (; d < s1; ++d) {
            int s = csr[d];
            ushort2 v = *(const ushort2*)(&xq[(size_t)s * CIN + c0]);
            acc.x += bf2f(v.x); acc.y += bf2f(v.y);
        }
        float dv = dinv[node];
        float2 o;
        o.x = acc.x * dv;
        o.y = acc.y * dv;
        *(float2*)(&u[(size_t)node * CIN + c0]) = o;
    }
}

// ---------------------------------------------------------------------------
// GEMM1 (post-agg): h1[i][c] = u[i,:] @ W1[:,c] + b1[c], fused BN stats.
// 64 rows/block, 16 rows/wave; per-block channel sums -> 1 atomic/channel.
// ---------------------------------------------------------------------------
__global__ __launch_bounds__(256) void gemm1_kernel(const float* __restrict__ u,
                                                    const float* __restrict__ W1,
                                                    const float* __restrict__ b1,
                                                    float* __restrict__ h1,
                                                    float* __restrict__ stats) {
    __shared__ float xs[64][CIN];  // 32 KB
    int tid = threadIdx.x;
    int rowBase = blockIdx.x * 64;

    const float4* ug = (const float4*)(u + (size_t)rowBase * CIN);
    float4* xsv = (float4*)(&xs[0][0]);
#pragma unroll
    for (int j = 0; j < 8; ++j) xsv[tid + j * 256] = ug[tid + j * 256];
    __syncthreads();

    int wave = tid >> 6, lane = tid & 63;
    int c0 = lane * 4;   // 64 lanes x 4 = 256 output channels
    int r0 = wave * 16;

    float4 acc[16];
#pragma unroll
    for (int r = 0; r < 16; ++r) acc[r] = make_float4(0.f, 0.f, 0.f, 0.f);

    for (int k = 0; k < CIN; k += 4) {
        float4 w0 = *(const float4*)(&W1[(k + 0) * CHID + c0]);
        float4 w1 = *(const float4*)(&W1[(k + 1) * CHID + c0]);
        float4 w2 = *(const float4*)(&W1[(k + 2) * CHID + c0]);
        float4 w3 = *(const float4*)(&W1[(k + 3) * CHID + c0]);
#pragma unroll
        for (int r = 0; r < 16; ++r) {
            float4 xv = *(const float4*)(&xs[r0 + r][k]);
            acc[r].x += xv.x * w0.x + xv.y * w1.x + xv.z * w2.x + xv.w * w3.x;
            acc[r].y += xv.x * w0.y + xv.y * w1.y + xv.z * w2.y + xv.w * w3.y;
            acc[r].z += xv.x * w0.z + xv.y * w1.z + xv.z * w2.z + xv.w * w3.z;
            acc[r].w += xv.x * w0.w + xv.y * w1.w + xv.z * w2.w + xv.w * w3.w;
        }
    }

    float4 bb = *(const float4*)(&b1[c0]);
    float4 ps = make_float4(0.f, 0.f, 0.f, 0.f);
    float4 pq = make_float4(0.f, 0.f, 0.f, 0.f);
#pragma unroll
    for (int r = 0; r < 16; ++r) {
        int row = rowBase + r0 + r;
        float4 h;
        h.x = acc[r].x + bb.x; h.y = acc[r].y + bb.y;
        h.z = acc[r].z + bb.z; h.w = acc[r].w + bb.w;
        *(float4*)(&h1[(size_t)row * CHID + c0]) = h;
        ps.x += h.x; ps.y += h.y; ps.z += h.z; ps.w += h.w;
        pq.x += h.x * h.x; pq.y += h.y * h.y; pq.z += h.z * h.z; pq.w += h.w * h.w;
    }

    __shared__ float red[4][CHID];  // 4 KB
    *(float4*)(&red[wave][c0]) = ps;
    __syncthreads();
    {
        int c = tid;  // 0..255
        float v = red[0][c] + red[1][c] + red[2][c] + red[3][c];
        atomicAdd(&stats[c], v);
    }
    __syncthreads();
    *(float4*)(&red[wave][c0]) = pq;
    __syncthreads();
    {
        int c = tid;
        float v = red[0][c] + red[1][c] + red[2][c] + red[3][c];
        atomicAdd(&stats[CHID + c], v);
    }
}

// ---------------------------------------------------------------------------
// BN prep: per-channel affine a*h+bb equivalent to BN(gamma,beta)
// ---------------------------------------------------------------------------
__global__ __launch_bounds__(256) void bnprep_kernel(const float* __restrict__ stats,
                                                     const float* __restrict__ gamma,
                                                     const float* __restrict__ beta,
                                                     float* __restrict__ ab) {
    int c = threadIdx.x;
    float mean = stats[c] * (1.0f / N_NODES);
    float var = stats[CHID + c] * (1.0f / N_NODES) - mean * mean;
    float a = gamma[c] / sqrtf(var + 1e-5f);
    ab[c] = a;
    ab[CHID + c] = beta[c] - mean * a;
}

// ---------------------------------------------------------------------------
// GEMM2: g2[i][o] = bf16( dinv[i] * ( relu(a*h1[i,:]+bb) @ W2[:,o] ) )
// affine+relu applied while staging rows into LDS; 64 rows/block.
// ---------------------------------------------------------------------------
__global__ __launch_bounds__(256) void gemm2_kernel(const float* __restrict__ h1,
                                                    const float* __restrict__ ab,
                                                    const float* __restrict__ W2,
                                                    const float* __restrict__ dinv,
                                                    unsigned short* __restrict__ g2) {
    __shared__ float xs[64][CHID];  // 64 KB
    int tid = threadIdx.x;
    int rowBase = blockIdx.x * 64;

    // (tid + j*256) & 63 == tid & 63  ->  affine coeffs are loop-invariant
    int c4 = (tid & 63) * 4;
    float4 a4 = *(const float4*)(&ab[c4]);
    float4 b4 = *(const float4*)(&ab[CHID + c4]);

    const float4* hg = (const float4*)(h1 + (size_t)rowBase * CHID);
#pragma unroll
    for (int j = 0; j < 16; ++j) {
        int idx = tid + j * 256;          // 4096 float4s = 64x256 floats
        float4 v = hg[idx];
        float4 r;
        r.x = fmaxf(v.x * a4.x + b4.x, 0.f);
        r.y = fmaxf(v.y * a4.y + b4.y, 0.f);
        r.z = fmaxf(v.z * a4.z + b4.z, 0.f);
        r.w = fmaxf(v.w * a4.w + b4.w, 0.f);
        ((float4*)(&xs[0][0]))[idx] = r;
    }
    __syncthreads();

    int wave = tid >> 6, lane = tid & 63;
    int o0 = lane * 2;  // 64 lanes x 2 = 128 outputs
    int r0 = wave * 16;

    float2 acc[16];
#pragma unroll
    for (int r = 0; r < 16; ++r) acc[r] = make_float2(0.f, 0.f);

    for (int k = 0; k < CHID; k += 4) {
        float2 w0 = *(const float2*)(&W2[(k + 0) * COUT + o0]);
        float2 w1 = *(const float2*)(&W2[(k + 1) * COUT + o0]);
        float2 w2 = *(const float2*)(&W2[(k + 2) * COUT + o0]);
        float2 w3 = *(const float2*)(&W2[(k + 3) * COUT + o0]);
#pragma unroll
        for (int r = 0; r < 16; ++r) {
            float4 xv = *(const float4*)(&xs[r0 + r][k]);
            acc[r].x += xv.x * w0.x + xv.y * w1.x + xv.z * w2.x + xv.w * w3.x;
            acc[r].y += xv.x * w0.y + xv.y * w1.y + xv.z * w2.y + xv.w * w3.y;
        }
    }

#pragma unroll
    for (int r = 0; r < 16; ++r) {
        int row = rowBase + r0 + r;
        float dv = dinv[row];
        ushort2 o;
        o.x = f2bf(acc[r].x * dv);
        o.y = f2bf(acc[r].y * dv);
        *(ushort2*)(&g2[(size_t)row * COUT + o0]) = o;  // 4B store
    }
}

// ---------------------------------------------------------------------------
// AGG2: out[i] = dinv[i]*(sum g2[src] + g2[i]) + b2
// same prefetched 8-deep pipeline (256B rows, ushort2 = 4B/lane).
// ---------------------------------------------------------------------------
__global__ __launch_bounds__(256) void agg2_kernel(const unsigned short* __restrict__ g2,
                                                   const int* __restrict__ offs,
                                                   const int* __restrict__ csr,
                                                   const float* __restrict__ dinv,
                                                   const float* __restrict__ b2,
                                                   float* __restrict__ out) {
    int tid = threadIdx.x, wave = tid >> 6, lane = tid & 63;
    int c0 = lane * 2;
    float2 b = *(const float2*)(&b2[c0]);

    for (int g = blockIdx.x; g < N_NODES / 4; g += gridDim.x) {
        int node = g * 4 + wave;
        int s0 = offs[node], s1 = offs[node + 1];
        ushort2 sv = *(const ushort2*)(&g2[(size_t)node * COUT + c0]);  // self loop
        float2 acc;
        acc.x = bf2f(sv.x); acc.y = bf2f(sv.y);

        int nb = (s1 - s0) >> 3;
        int d = s0;
        int i0 = 0, i1 = 0, i2 = 0, i3 = 0, i4 = 0, i5 = 0, i6 = 0, i7 = 0;
        if (nb > 0) {
            i0 = csr[d + 0]; i1 = csr[d + 1]; i2 = csr[d + 2]; i3 = csr[d + 3];
            i4 = csr[d + 4]; i5 = csr[d + 5]; i6 = csr[d + 6]; i7 = csr[d + 7];
        }
        for (int t = 0; t < nb; ++t) {
            ushort2 v0 = *(const ushort2*)(&g2[(size_t)i0 * COUT + c0]);
            ushort2 v1 = *(const ushort2*)(&g2[(size_t)i1 * COUT + c0]);
            ushort2 v2 = *(const ushort2*)(&g2[(size_t)i2 * COUT + c0]);
            ushort2 v3 = *(const ushort2*)(&g2[(size_t)i3 * COUT + c0]);
            ushort2 v4 = *(const ushort2*)(&g2[(size_t)i4 * COUT + c0]);
            ushort2 v5 = *(const ushort2*)(&g2[(size_t)i5 * COUT + c0]);
            ushort2 v6 = *(const ushort2*)(&g2[(size_t)i6 * COUT + c0]);
            ushort2 v7 = *(const ushort2*)(&g2[(size_t)i7 * COUT + c0]);
            int nd = d + 8;
            int j0 = 0, j1 = 0, j2 = 0, j3 = 0, j4 = 0, j5 = 0, j6 = 0, j7 = 0;
            if (t + 1 < nb) {
                j0 = csr[nd + 0]; j1 = csr[nd + 1]; j2 = csr[nd + 2]; j3 = csr[nd + 3];
                j4 = csr[nd + 4]; j5 = csr[nd + 5]; j6 = csr[nd + 6]; j7 = csr[nd + 7];
            }
            acc.x += ((bf2f(v0.x) + bf2f(v1.x)) + (bf2f(v2.x) + bf2f(v3.x))) +
                     ((bf2f(v4.x) + bf2f(v5.x)) + (bf2f(v6.x) + bf2f(v7.x)));
            acc.y += ((bf2f(v0.y) + bf2f(v1.y)) + (bf2f(v2.y) + bf2f(v3.y))) +
                     ((bf2f(v4.y) + bf2f(v5.y)) + (bf2f(v6.y) + bf2f(v7.y)));
            d = nd;
            i0 = j0; i1 = j1; i2 = j2; i3 = j3; i4 = j4; i5 = j5; i6 = j6; i7 = j7;
        }
        for (; d + 4 <= s1; d += 4) {
            int k0 = csr[d + 0], k1 = csr[d + 1], k2 = csr[d + 2], k3 = csr[d + 3];
            ushort2 v0 = *(const ushort2*)(&g2[(size_t)k0 * COUT + c0]);
            ushort2 v1 = *(const ushort2*)(&g2[(size_t)k1 * COUT + c0]);
            ushort2 v2 = *(const ushort2*)(&g2[(size_t)k2 * COUT + c0]);
            ushort2 v3 = *(const ushort2*)(&g2[(size_t)k3 * COUT + c0]);
            acc.x += (bf2f(v0.x) + bf2f(v1.x)) + (bf2f(v2.x) + bf2f(v3.x));
            acc.y += (bf2f(v0.y) + bf2f(v1.y)) + (bf2f(v2.y) + bf2f(v3.y));
        }
        for (; d < s1; ++d) {
            int s = csr[d];
            ushort2 v = *(const ushort2*)(&g2[(size_t)s * COUT + c0]);
            acc.x += bf2f(v.x); acc.y += bf2f(v.y);
        }
        float dv = dinv[node];
        float2 o;
        o.x = acc.x * dv + b.x;
        o.y = acc.y * dv + b.y;
        *(float2*)(&out[(size_t)node * COUT + c0]) = o;
    }
}

// ---------------------------------------------------------------------------
extern "C" void kernel_launch(void* const* d_in, const int* in_sizes, int n_in,
                              void* d_out, int out_size, void* d_ws, size_t ws_size,
                              hipStream_t stream) {
    const float* x     = (const float*)d_in[0];
    const int*   ei    = (const int*)d_in[1];
    const float* W1    = (const float*)d_in[2];
    const float* b1    = (const float*)d_in[3];
    const float* gamma = (const float*)d_in[4];
    const float* beta  = (const float*)d_in[5];
    const float* W2    = (const float*)d_in[6];
    const float* b2    = (const float*)d_in[7];
    float* out = (float*)d_out;

    const int* srcv = ei;            // edge_index[0]
    const int* dstv = ei + E_EDGES;  // edge_index[1]

    // workspace layout (g2 aliases xq: xq dead after aggx)
    char* ws = (char*)d_ws;
    size_t off = 0;
    auto alloc = [&](size_t bytes) -> void* {
        void* p = ws + off;
        off += (bytes + 255) & ~(size_t)255;
        return p;
    };
    int*   deg    = (int*)alloc((size_t)N_NODES * 4);
    int*   offs   = (int*)alloc((size_t)(N_NODES + 1) * 4);
    int*   cursor = (int*)alloc((size_t)N_NODES * 4);
    float* dinv   = (float*)alloc((size_t)N_NODES * 4);
    int*   csr    = (int*)alloc((size_t)E_EDGES * 4);
    unsigned short* xq = (unsigned short*)alloc((size_t)N_NODES * CIN * 2);   // 8 MB, also g2
    float* u      = (float*)alloc((size_t)N_NODES * CIN * 4);                 // 16 MB
    float* h1     = (float*)alloc((size_t)N_NODES * CHID * 4);                // 32 MB
    float* stats  = (float*)alloc(2 * CHID * 4);
    float* ab     = (float*)alloc(2 * CHID * 4);
    unsigned short* g2 = xq;

    hipMemsetAsync(deg, 0, (size_t)N_NODES * 4, stream);
    hipMemsetAsync(stats, 0, 2 * CHID * 4, stream);

    deg_kernel<<<E_EDGES / 256, 256, 0, stream>>>(dstv, deg);
    scan_kernel<<<1, 1024, 0, stream>>>(deg, offs, cursor, dinv);
    fill_kernel<<<E_EDGES / 256, 256, 0, stream>>>(srcv, dstv, cursor, csr);

    quantx_kernel<<<N_NODES * CIN / 4 / 256, 256, 0, stream>>>(x, dinv, xq);
    aggx_kernel<<<2048, 256, 0, stream>>>(xq, offs, csr, dinv, u);
    gemm1_kernel<<<N_NODES / 64, 256, 0, stream>>>(u, W1, b1, h1, stats);
    bnprep_kernel<<<1, 256, 0, stream>>>(stats, gamma, beta, ab);
    gemm2_kernel<<<N_NODES / 64, 256, 0, stream>>>(h1, ab, W2, dinv, g2);
    agg2_kernel<<<2048, 256, 0, stream>>>(g2, offs, csr, dinv, b2, out);
}

// Round 10
// 375.422 us; speedup vs baseline: 1.4242x; 1.0623x over previous
//
#include <hip/hip_runtime.h>
#include <hip/hip_bf16.h>
#include <math.h>

#define N_NODES 32768
#define E_EDGES 1048576
#define CIN 128
#define CHID 256
#define COUT 128

// bf16 <-> f32 helpers. Gather tables (x~, g2) stored bf16: R6 evidence says
// the agg path is bytes+requests bound, so smaller rows are the lever.
__device__ inline float bf2f(unsigned short u) {
    union { unsigned int i; float f; } c;
    c.i = ((unsigned int)u) << 16;
    return c.f;
}
__device__ inline unsigned short f2bf(float f) {
    __hip_bfloat16 h = __float2bfloat16(f);  // RNE
    return *reinterpret_cast<unsigned short*>(&h);
}

// ---------------------------------------------------------------------------
// CSR build: deg count -> exclusive scan (+dinv) -> fill
// R9 evidence: 1-edge/thread fill = 84us, VALUBusy 0.3%, 11% HBM -> pure
// atomic-latency bound. 4 edges/thread (int4 loads) => 4 independent
// atomic+store chains per lane, 4x fewer waves (all resident in one shot).
// ---------------------------------------------------------------------------
__global__ __launch_bounds__(256) void deg_kernel(const int* __restrict__ dst,
                                                  int* __restrict__ deg) {
    int idx = blockIdx.x * blockDim.x + threadIdx.x;  // int4 index
    int4 d4 = ((const int4*)dst)[idx];
    atomicAdd(&deg[d4.x], 1);
    atomicAdd(&deg[d4.y], 1);
    atomicAdd(&deg[d4.z], 1);
    atomicAdd(&deg[d4.w], 1);
}

__global__ __launch_bounds__(1024) void scan_kernel(const int* __restrict__ deg,
                                                    int* __restrict__ offs,
                                                    int* __restrict__ cursor,
                                                    float* __restrict__ dinv) {
    __shared__ int s[1024];
    int t = threadIdx.x;
    int base = t * 32;  // 1024 threads x 32 = 32768
    int ts = 0;
#pragma unroll
    for (int j = 0; j < 32; ++j) ts += deg[base + j];
    s[t] = ts;
    __syncthreads();
    // Hillis-Steele inclusive scan over 1024 thread-sums (double-barrier form)
    for (int off = 1; off < 1024; off <<= 1) {
        int v = (t >= off) ? s[t - off] : 0;
        __syncthreads();
        s[t] += v;
        __syncthreads();
    }
    int run = s[t] - ts;  // exclusive prefix for this chunk
    for (int j = 0; j < 32; ++j) {
        int idx = base + j;
        int d = deg[idx];
        offs[idx] = run;
        cursor[idx] = run;
        // reference deg includes the self-loop: indeg + 1 (always >= 1)
        dinv[idx] = 1.0f / sqrtf((float)(d + 1));
        run += d;
    }
    if (t == 1023) offs[N_NODES] = s[1023];
}

__global__ __launch_bounds__(256) void fill_kernel(const int* __restrict__ src,
                                                   const int* __restrict__ dst,
                                                   int* __restrict__ cursor,
                                                   int* __restrict__ csr) {
    int idx = blockIdx.x * blockDim.x + threadIdx.x;  // int4 index
    int4 d4 = ((const int4*)dst)[idx];
    int4 s4 = ((const int4*)src)[idx];
    // 4 independent atomic round-trips in flight per lane
    int p0 = atomicAdd(&cursor[d4.x], 1);
    int p1 = atomicAdd(&cursor[d4.y], 1);
    int p2 = atomicAdd(&cursor[d4.z], 1);
    int p3 = atomicAdd(&cursor[d4.w], 1);
    csr[p0] = s4.x;
    csr[p1] = s4.y;
    csr[p2] = s4.z;
    csr[p3] = s4.w;
}

// ---------------------------------------------------------------------------
// QUANTX: xq[i][c] = bf16( x[i][c] * dinv[i] )   (256B rows for the gather)
// ---------------------------------------------------------------------------
__global__ __launch_bounds__(256) void quantx_kernel(const float* __restrict__ x,
                                                     const float* __restrict__ dinv,
                                                     unsigned short* __restrict__ xq) {
    int idx = blockIdx.x * 256 + threadIdx.x;  // float4 index; N*CIN/4 total
    int row = idx >> 5;                        // 32 float4s per 128-ch row
    float dv = dinv[row];
    float4 v = ((const float4*)x)[idx];
    ushort4 o;
    o.x = f2bf(v.x * dv); o.y = f2bf(v.y * dv);
    o.z = f2bf(v.z * dv); o.w = f2bf(v.w * dv);
    ((ushort4*)xq)[idx] = o;
}

// ---------------------------------------------------------------------------
// AGGX: u[i] = dinv[i]*(sum_{e:dst=i} xq[src] + xq[i])      (layer-1 agg in
// the 128-dim INPUT space: agg commutes with @W1, so gather 256B rows not
// 512B). One wave per node; lane owns 2 channels (ushort2 = 4B/lane);
// 8-deep gather pipeline with next-batch index prefetch; f32 accum.
// ---------------------------------------------------------------------------
__global__ __launch_bounds__(256) void aggx_kernel(const unsigned short* __restrict__ xq,
                                                   const int* __restrict__ offs,
                                                   const int* __restrict__ csr,
                                                   const float* __restrict__ dinv,
                                                   float* __restrict__ u) {
    int tid = threadIdx.x, wave = tid >> 6, lane = tid & 63;
    int c0 = lane * 2;

    for (int g = blockIdx.x; g < N_NODES / 4; g += gridDim.x) {
        int node = g * 4 + wave;
        int s0 = offs[node], s1 = offs[node + 1];
        ushort2 sv = *(const ushort2*)(&xq[(size_t)node * CIN + c0]);  // self loop
        float2 acc;
        acc.x = bf2f(sv.x); acc.y = bf2f(sv.y);

        int nb = (s1 - s0) >> 3;
        int d = s0;
        int i0 = 0, i1 = 0, i2 = 0, i3 = 0, i4 = 0, i5 = 0, i6 = 0, i7 = 0;
        if (nb > 0) {
            i0 = csr[d + 0]; i1 = csr[d + 1]; i2 = csr[d + 2]; i3 = csr[d + 3];
            i4 = csr[d + 4]; i5 = csr[d + 5]; i6 = csr[d + 6]; i7 = csr[d + 7];
        }
        for (int t = 0; t < nb; ++t) {
            ushort2 v0 = *(const ushort2*)(&xq[(size_t)i0 * CIN + c0]);
            ushort2 v1 = *(const ushort2*)(&xq[(size_t)i1 * CIN + c0]);
            ushort2 v2 = *(const ushort2*)(&xq[(size_t)i2 * CIN + c0]);
            ushort2 v3 = *(const ushort2*)(&xq[(size_t)i3 * CIN + c0]);
            ushort2 v4 = *(const ushort2*)(&xq[(size_t)i4 * CIN + c0]);
            ushort2 v5 = *(const ushort2*)(&xq[(size_t)i5 * CIN + c0]);
            ushort2 v6 = *(const ushort2*)(&xq[(size_t)i6 * CIN + c0]);
            ushort2 v7 = *(const ushort2*)(&xq[(size_t)i7 * CIN + c0]);
            int nd = d + 8;
            int j0 = 0, j1 = 0, j2 = 0, j3 = 0, j4 = 0, j5 = 0, j6 = 0, j7 = 0;
            if (t + 1 < nb) {
                j0 = csr[nd + 0]; j1 = csr[nd + 1]; j2 = csr[nd + 2]; j3 = csr[nd + 3];
                j4 = csr[nd + 4]; j5 = csr[nd + 5]; j6 = csr[nd + 6]; j7 = csr[nd + 7];
            }
            acc.x += ((bf2f(v0.x) + bf2f(v1.x)) + (bf2f(v2.x) + bf2f(v3.x))) +
                     ((bf2f(v4.x) + bf2f(v5.x)) + (bf2f(v6.x) + bf2f(v7.x)));
            acc.y += ((bf2f(v0.y) + bf2f(v1.y)) + (bf2f(v2.y) + bf2f(v3.y))) +
                     ((bf2f(v4.y) + bf2f(v5.y)) + (bf2f(v6.y) + bf2f(v7.y)));
            d = nd;
            i0 = j0; i1 = j1; i2 = j2; i3 = j3; i4 = j4; i5 = j5; i6 = j6; i7 = j7;
        }
        for (; d + 4 <= s1; d += 4) {
            int k0 = csr[d + 0], k1 = csr[d + 1], k2 = csr[d + 2], k3 = csr[d + 3];
            ushort2 v0 = *(const ushort2*)(&xq[(size_t)k0 * CIN + c0]);
            ushort2 v1 = *(const ushort2*)(&xq[(size_t)k1 * CIN + c0]);
            ushort2 v2 = *(const ushort2*)(&xq[(size_t)k2 * CIN + c0]);
            ushort2 v3 = *(const ushort2*)(&xq[(size_t)k3 * CIN + c0]);
            acc.x += (bf2f(v0.x) + bf2f(v1.x)) + (bf2f(v2.x) + bf2f(v3.x));
            acc.y += (bf2f(v0.y) + bf2f(v1.y)) + (bf2f(v2.y) + bf2f(v3.y));
        }
        for (; d < s1; ++d) {
            int s = csr[d];
            ushort2 v = *(const ushort2*)(&xq[(size_t)s * CIN + c0]);
            acc.x += bf2f(v.x); acc.y += bf2f(v.y);
        }
        float dv = dinv[node];
        float2 o;
        o.x = acc.x * dv;
        o.y = acc.y * dv;
        *(float2*)(&u[(size_t)node * CIN + c0]) = o;
    }
}

// ---------------------------------------------------------------------------
// GEMM1 (post-agg): h1[i][c] = u[i,:] @ W1[:,c] + b1[c], fused BN stats.
// 64 rows/block, 16 rows/wave; per-block channel sums -> 1 atomic/channel.
// ---------------------------------------------------------------------------
__global__ __launch_bounds__(256) void gemm1_kernel(const float* __restrict__ u,
                                                    const float* __restrict__ W1,
                                                    const float* __restrict__ b1,
                                                    float* __restrict__ h1,
                                                    float* __restrict__ stats) {
    __shared__ float xs[64][CIN];  // 32 KB
    int tid = threadIdx.x;
    int rowBase = blockIdx.x * 64;

    const float4* ug = (const float4*)(u + (size_t)rowBase * CIN);
    float4* xsv = (float4*)(&xs[0][0]);
#pragma unroll
    for (int j = 0; j < 8; ++j) xsv[tid + j * 256] = ug[tid + j * 256];
    __syncthreads();

    int wave = tid >> 6, lane = tid & 63;
    int c0 = lane * 4;   // 64 lanes x 4 = 256 output channels
    int r0 = wave * 16;

    float4 acc[16];
#pragma unroll
    for (int r = 0; r < 16; ++r) acc[r] = make_float4(0.f, 0.f, 0.f, 0.f);

    for (int k = 0; k < CIN; k += 4) {
        float4 w0 = *(const float4*)(&W1[(k + 0) * CHID + c0]);
        float4 w1 = *(const float4*)(&W1[(k + 1) * CHID + c0]);
        float4 w2 = *(const float4*)(&W1[(k + 2) * CHID + c0]);
        float4 w3 = *(const float4*)(&W1[(k + 3) * CHID + c0]);
#pragma unroll
        for (int r = 0; r < 16; ++r) {
            float4 xv = *(const float4*)(&xs[r0 + r][k]);
            acc[r].x += xv.x * w0.x + xv.y * w1.x + xv.z * w2.x + xv.w * w3.x;
            acc[r].y += xv.x * w0.y + xv.y * w1.y + xv.z * w2.y + xv.w * w3.y;
            acc[r].z += xv.x * w0.z + xv.y * w1.z + xv.z * w2.z + xv.w * w3.z;
            acc[r].w += xv.x * w0.w + xv.y * w1.w + xv.z * w2.w + xv.w * w3.w;
        }
    }

    float4 bb = *(const float4*)(&b1[c0]);
    float4 ps = make_float4(0.f, 0.f, 0.f, 0.f);
    float4 pq = make_float4(0.f, 0.f, 0.f, 0.f);
#pragma unroll
    for (int r = 0; r < 16; ++r) {
        int row = rowBase + r0 + r;
        float4 h;
        h.x = acc[r].x + bb.x; h.y = acc[r].y + bb.y;
        h.z = acc[r].z + bb.z; h.w = acc[r].w + bb.w;
        *(float4*)(&h1[(size_t)row * CHID + c0]) = h;
        ps.x += h.x; ps.y += h.y; ps.z += h.z; ps.w += h.w;
        pq.x += h.x * h.x; pq.y += h.y * h.y; pq.z += h.z * h.z; pq.w += h.w * h.w;
    }

    __shared__ float red[4][CHID];  // 4 KB
    *(float4*)(&red[wave][c0]) = ps;
    __syncthreads();
    {
        int c = tid;  // 0..255
        float v = red[0][c] + red[1][c] + red[2][c] + red[3][c];
        atomicAdd(&stats[c], v);
    }
    __syncthreads();
    *(float4*)(&red[wave][c0]) = pq;
    __syncthreads();
    {
        int c = tid;
        float v = red[0][c] + red[1][c] + red[2][c] + red[3][c];
        atomicAdd(&stats[CHID + c], v);
    }
}

// ---------------------------------------------------------------------------
// BN prep: per-channel affine a*h+bb equivalent to BN(gamma,beta)
// ---------------------------------------------------------------------------
__global__ __launch_bounds__(256) void bnprep_kernel(const float* __restrict__ stats,
                                                     const float* __restrict__ gamma,
                                                     const float* __restrict__ beta,
                                                     float* __restrict__ ab) {
    int c = threadIdx.x;
    float mean = stats[c] * (1.0f / N_NODES);
    float var = stats[CHID + c] * (1.0f / N_NODES) - mean * mean;
    float a = gamma[c] / sqrtf(var + 1e-5f);
    ab[c] = a;
    ab[CHID + c] = beta[c] - mean * a;
}

// ---------------------------------------------------------------------------
// GEMM2: g2[i][o] = bf16( dinv[i] * ( relu(a*h1[i,:]+bb) @ W2[:,o] ) )
// affine+relu applied while staging rows into LDS; 64 rows/block.
// ---------------------------------------------------------------------------
__global__ __launch_bounds__(256) void gemm2_kernel(const float* __restrict__ h1,
                                                    const float* __restrict__ ab,
                                                    const float* __restrict__ W2,
                                                    const float* __restrict__ dinv,
                                                    unsigned short* __restrict__ g2) {
    __shared__ float xs[64][CHID];  // 64 KB
    int tid = threadIdx.x;
    int rowBase = blockIdx.x * 64;

    // (tid + j*256) & 63 == tid & 63  ->  affine coeffs are loop-invariant
    int c4 = (tid & 63) * 4;
    float4 a4 = *(const float4*)(&ab[c4]);
    float4 b4 = *(const float4*)(&ab[CHID + c4]);

    const float4* hg = (const float4*)(h1 + (size_t)rowBase * CHID);
#pragma unroll
    for (int j = 0; j < 16; ++j) {
        int idx = tid + j * 256;          // 4096 float4s = 64x256 floats
        float4 v = hg[idx];
        float4 r;
        r.x = fmaxf(v.x * a4.x + b4.x, 0.f);
        r.y = fmaxf(v.y * a4.y + b4.y, 0.f);
        r.z = fmaxf(v.z * a4.z + b4.z, 0.f);
        r.w = fmaxf(v.w * a4.w + b4.w, 0.f);
        ((float4*)(&xs[0][0]))[idx] = r;
    }
    __syncthreads();

    int wave = tid >> 6, lane = tid & 63;
    int o0 = lane * 2;  // 64 lanes x 2 = 128 outputs
    int r0 = wave * 16;

    float2 acc[16];
#pragma unroll
    for (int r = 0; r < 16; ++r) acc[r] = make_float2(0.f, 0.f);

    for (int k = 0; k < CHID; k += 4) {
        float2 w0 = *(const float2*)(&W2[(k + 0) * COUT + o0]);
        float2 w1 = *(const float2*)(&W2[(k + 1) * COUT + o0]);
        float2 w2 = *(const float2*)(&W2[(k + 2) * COUT + o0]);
        float2 w3 = *(const float2*)(&W2[(k + 3) * COUT + o0]);
#pragma unroll
        for (int r = 0; r < 16; ++r) {
            float4 xv = *(const float4*)(&xs[r0 + r][k]);
            acc[r].x += xv.x * w0.x + xv.y * w1.x + xv.z * w2.x + xv.w * w3.x;
            acc[r].y += xv.x * w0.y + xv.y * w1.y + xv.z * w2.y + xv.w * w3.y;
        }
    }

#pragma unroll
    for (int r = 0; r < 16; ++r) {
        int row = rowBase + r0 + r;
        float dv = dinv[row];
        ushort2 o;
        o.x = f2bf(acc[r].x * dv);
        o.y = f2bf(acc[r].y * dv);
        *(ushort2*)(&g2[(size_t)row * COUT + o0]) = o;  // 4B store
    }
}

// ---------------------------------------------------------------------------
// AGG2: out[i] = dinv[i]*(sum g2[src] + g2[i]) + b2
// same prefetched 8-deep pipeline (256B rows, ushort2 = 4B/lane).
// ---------------------------------------------------------------------------
__global__ __launch_bounds__(256) void agg2_kernel(const unsigned short* __restrict__ g2,
                                                   const int* __restrict__ offs,
                                                   const int* __restrict__ csr,
                                                   const float* __restrict__ dinv,
                                                   const float* __restrict__ b2,
                                                   float* __restrict__ out) {
    int tid = threadIdx.x, wave = tid >> 6, lane = tid & 63;
    int c0 = lane * 2;
    float2 b = *(const float2*)(&b2[c0]);

    for (int g = blockIdx.x; g < N_NODES / 4; g += gridDim.x) {
        int node = g * 4 + wave;
        int s0 = offs[node], s1 = offs[node + 1];
        ushort2 sv = *(const ushort2*)(&g2[(size_t)node * COUT + c0]);  // self loop
        float2 acc;
        acc.x = bf2f(sv.x); acc.y = bf2f(sv.y);

        int nb = (s1 - s0) >> 3;
        int d = s0;
        int i0 = 0, i1 = 0, i2 = 0, i3 = 0, i4 = 0, i5 = 0, i6 = 0, i7 = 0;
        if (nb > 0) {
            i0 = csr[d + 0]; i1 = csr[d + 1]; i2 = csr[d + 2]; i3 = csr[d + 3];
            i4 = csr[d + 4]; i5 = csr[d + 5]; i6 = csr[d + 6]; i7 = csr[d + 7];
        }
        for (int t = 0; t < nb; ++t) {
            ushort2 v0 = *(const ushort2*)(&g2[(size_t)i0 * COUT + c0]);
            ushort2 v1 = *(const ushort2*)(&g2[(size_t)i1 * COUT + c0]);
            ushort2 v2 = *(const ushort2*)(&g2[(size_t)i2 * COUT + c0]);
            ushort2 v3 = *(const ushort2*)(&g2[(size_t)i3 * COUT + c0]);
            ushort2 v4 = *(const ushort2*)(&g2[(size_t)i4 * COUT + c0]);
            ushort2 v5 = *(const ushort2*)(&g2[(size_t)i5 * COUT + c0]);
            ushort2 v6 = *(const ushort2*)(&g2[(size_t)i6 * COUT + c0]);
            ushort2 v7 = *(const ushort2*)(&g2[(size_t)i7 * COUT + c0]);
            int nd = d + 8;
            int j0 = 0, j1 = 0, j2 = 0, j3 = 0, j4 = 0, j5 = 0, j6 = 0, j7 = 0;
            if (t + 1 < nb) {
                j0 = csr[nd + 0]; j1 = csr[nd + 1]; j2 = csr[nd + 2]; j3 = csr[nd + 3];
                j4 = csr[nd + 4]; j5 = csr[nd + 5]; j6 = csr[nd + 6]; j7 = csr[nd + 7];
            }
            acc.x += ((bf2f(v0.x) + bf2f(v1.x)) + (bf2f(v2.x) + bf2f(v3.x))) +
                     ((bf2f(v4.x) + bf2f(v5.x)) + (bf2f(v6.x) + bf2f(v7.x)));
            acc.y += ((bf2f(v0.y) + bf2f(v1.y)) + (bf2f(v2.y) + bf2f(v3.y))) +
                     ((bf2f(v4.y) + bf2f(v5.y)) + (bf2f(v6.y) + bf2f(v7.y)));
            d = nd;
            i0 = j0; i1 = j1; i2 = j2; i3 = j3; i4 = j4; i5 = j5; i6 = j6; i7 = j7;
        }
        for (; d + 4 <= s1; d += 4) {
            int k0 = csr[d + 0], k1 = csr[d + 1], k2 = csr[d + 2], k3 = csr[d + 3];
            ushort2 v0 = *(const ushort2*)(&g2[(size_t)k0 * COUT + c0]);
            ushort2 v1 = *(const ushort2*)(&g2[(size_t)k1 * COUT + c0]);
            ushort2 v2 = *(const ushort2*)(&g2[(size_t)k2 * COUT + c0]);
            ushort2 v3 = *(const ushort2*)(&g2[(size_t)k3 * COUT + c0]);
            acc.x += (bf2f(v0.x) + bf2f(v1.x)) + (bf2f(v2.x) + bf2f(v3.x));
            acc.y += (bf2f(v0.y) + bf2f(v1.y)) + (bf2f(v2.y) + bf2f(v3.y));
        }
        for (; d < s1; ++d) {
            int s = csr[d];
            ushort2 v = *(const ushort2*)(&g2[(size_t)s * COUT + c0]);
            acc.x += bf2f(v.x); acc.y += bf2f(v.y);
        }
        float dv = dinv[node];
        float2 o;
        o.x = acc.x * dv + b.x;
        o.y = acc.y * dv + b.y;
        *(float2*)(&out[(size_t)node * COUT + c0]) = o;
    }
}

// ---------------------------------------------------------------------------
extern "C" void kernel_launch(void* const* d_in, const int* in_sizes, int n_in,
                              void* d_out, int out_size, void* d_ws, size_t ws_size,
                              hipStream_t stream) {
    const float* x     = (const float*)d_in[0];
    const int*   ei    = (const int*)d_in[1];
    const float* W1    = (const float*)d_in[2];
    const float* b1    = (const float*)d_in[3];
    const float* gamma = (const float*)d_in[4];
    const float* beta  = (const float*)d_in[5];
    const float* W2    = (const float*)d_in[6];
    const float* b2    = (const float*)d_in[7];
    float* out = (float*)d_out;

    const int* srcv = ei;            // edge_index[0]
    const int* dstv = ei + E_EDGES;  // edge_index[1]

    // workspace layout (g2 aliases xq: xq dead after aggx)
    char* ws = (char*)d_ws;
    size_t off = 0;
    auto alloc = [&](size_t bytes) -> void* {
        void* p = ws + off;
        off += (bytes + 255) & ~(size_t)255;
        return p;
    };
    int*   deg    = (int*)alloc((size_t)N_NODES * 4);
    int*   offs   = (int*)alloc((size_t)(N_NODES + 1) * 4);
    int*   cursor = (int*)alloc((size_t)N_NODES * 4);
    float* dinv   = (float*)alloc((size_t)N_NODES * 4);
    int*   csr    = (int*)alloc((size_t)E_EDGES * 4);
    unsigned short* xq = (unsigned short*)alloc((size_t)N_NODES * CIN * 2);   // 8 MB, also g2
    float* u      = (float*)alloc((size_t)N_NODES * CIN * 4);                 // 16 MB
    float* h1     = (float*)alloc((size_t)N_NODES * CHID * 4);                // 32 MB
    float* stats  = (float*)alloc(2 * CHID * 4);
    float* ab     = (float*)alloc(2 * CHID * 4);
    unsigned short* g2 = xq;

    hipMemsetAsync(deg, 0, (size_t)N_NODES * 4, stream);
    hipMemsetAsync(stats, 0, 2 * CHID * 4, stream);

    deg_kernel<<<E_EDGES / 4 / 256, 256, 0, stream>>>(dstv, deg);
    scan_kernel<<<1, 1024, 0, stream>>>(deg, offs, cursor, dinv);
    fill_kernel<<<E_EDGES / 4 / 256, 256, 0, stream>>>(srcv, dstv, cursor, csr);

    quantx_kernel<<<N_NODES * CIN / 4 / 256, 256, 0, stream>>>(x, dinv, xq);
    aggx_kernel<<<2048, 256, 0, stream>>>(xq, offs, csr, dinv, u);
    gemm1_kernel<<<N_NODES / 64, 256, 0, stream>>>(u, W1, b1, h1, stats);
    bnprep_kernel<<<1, 256, 0, stream>>>(stats, gamma, beta, ab);
    gemm2_kernel<<<N_NODES / 64, 256, 0, stream>>>(h1, ab, W2, dinv, g2);
    agg2_kernel<<<2048, 256, 0, stream>>>(g2, offs, csr, dinv, b2, out);
}

// Round 11
// 325.142 us; speedup vs baseline: 1.6445x; 1.1546x over previous
//
#include <hip/hip_runtime.h>
#include <hip/hip_bf16.h>
#include <math.h>

#define N_NODES 32768
#define E_EDGES 1048576
#define CIN 128
#define CHID 256
#define COUT 128

// bf16 <-> f32 helpers. Gather tables (x~, g2) stored bf16: R6 evidence says
// the agg path is bytes+requests bound, so smaller rows are the lever.
__device__ inline float bf2f(unsigned short u) {
    union { unsigned int i; float f; } c;
    c.i = ((unsigned int)u) << 16;
    return c.f;
}
__device__ inline unsigned short f2bf(float f) {
    __hip_bfloat16 h = __float2bfloat16(f);  // RNE
    return *reinterpret_cast<unsigned short*>(&h);
}

// ---------------------------------------------------------------------------
// CSR build: deg+rank count -> exclusive scan (+dinv) -> atomic-free fill
// R10 evidence: atomic->dependent-store chain in fill is the serializer
// (72us, VALUBusy 0.2%, occupancy-insensitive). The deg pass's atomicAdd
// return value IS the edge's slot within its dst segment -> persist it
// (rank[e]) and fill becomes atomic-free fire-and-forget scatter.
// ---------------------------------------------------------------------------
__global__ __launch_bounds__(256) void deg_kernel(const int* __restrict__ dst,
                                                  int* __restrict__ deg,
                                                  int* __restrict__ rank) {
    int idx = blockIdx.x * blockDim.x + threadIdx.x;  // int2 index
    int2 d2 = ((const int2*)dst)[idx];
    int r0 = atomicAdd(&deg[d2.x], 1);   // 2 independent atomic chains/lane,
    int r1 = atomicAdd(&deg[d2.y], 1);   // 2048 blocks -> full occupancy
    int2 r2; r2.x = r0; r2.y = r1;
    ((int2*)rank)[idx] = r2;             // sequential 8B store
}

__global__ __launch_bounds__(1024) void scan_kernel(const int* __restrict__ deg,
                                                    int* __restrict__ offs,
                                                    float* __restrict__ dinv) {
    __shared__ int s[1024];
    int t = threadIdx.x;
    int base = t * 32;  // 1024 threads x 32 = 32768
    int ts = 0;
#pragma unroll
    for (int j = 0; j < 32; ++j) ts += deg[base + j];
    s[t] = ts;
    __syncthreads();
    // Hillis-Steele inclusive scan over 1024 thread-sums (double-barrier form)
    for (int off = 1; off < 1024; off <<= 1) {
        int v = (t >= off) ? s[t - off] : 0;
        __syncthreads();
        s[t] += v;
        __syncthreads();
    }
    int run = s[t] - ts;  // exclusive prefix for this chunk
    for (int j = 0; j < 32; ++j) {
        int idx = base + j;
        int d = deg[idx];
        offs[idx] = run;
        // reference deg includes the self-loop: indeg + 1 (always >= 1)
        dinv[idx] = 1.0f / sqrtf((float)(d + 1));
        run += d;
    }
    if (t == 1023) offs[N_NODES] = s[1023];
}

__global__ __launch_bounds__(256) void fill_kernel(const int* __restrict__ src,
                                                   const int* __restrict__ dst,
                                                   const int* __restrict__ rank,
                                                   const int* __restrict__ offs,
                                                   int* __restrict__ csr) {
    int idx = blockIdx.x * blockDim.x + threadIdx.x;  // int4 index
    int4 d4 = ((const int4*)dst)[idx];
    int4 s4 = ((const int4*)src)[idx];
    int4 r4 = ((const int4*)rank)[idx];
    // offs is 128KB -> L2-resident; gathers cheap. Stores fire-and-forget.
    csr[offs[d4.x] + r4.x] = s4.x;
    csr[offs[d4.y] + r4.y] = s4.y;
    csr[offs[d4.z] + r4.z] = s4.z;
    csr[offs[d4.w] + r4.w] = s4.w;
}

// ---------------------------------------------------------------------------
// QUANTX: xq[i][c] = bf16( x[i][c] * dinv[i] )   (256B rows for the gather)
// ---------------------------------------------------------------------------
__global__ __launch_bounds__(256) void quantx_kernel(const float* __restrict__ x,
                                                     const float* __restrict__ dinv,
                                                     unsigned short* __restrict__ xq) {
    int idx = blockIdx.x * 256 + threadIdx.x;  // float4 index; N*CIN/4 total
    int row = idx >> 5;                        // 32 float4s per 128-ch row
    float dv = dinv[row];
    float4 v = ((const float4*)x)[idx];
    ushort4 o;
    o.x = f2bf(v.x * dv); o.y = f2bf(v.y * dv);
    o.z = f2bf(v.z * dv); o.w = f2bf(v.w * dv);
    ((ushort4*)xq)[idx] = o;
}

// ---------------------------------------------------------------------------
// AGGX: u[i] = dinv[i]*(sum_{e:dst=i} xq[src] + xq[i])      (layer-1 agg in
// the 128-dim INPUT space: agg commutes with @W1, so gather 256B rows not
// 512B). One wave per node; lane owns 2 channels (ushort2 = 4B/lane);
// 8-deep gather pipeline with next-batch index prefetch; f32 accum.
// ---------------------------------------------------------------------------
__global__ __launch_bounds__(256) void aggx_kernel(const unsigned short* __restrict__ xq,
                                                   const int* __restrict__ offs,
                                                   const int* __restrict__ csr,
                                                   const float* __restrict__ dinv,
                                                   float* __restrict__ u) {
    int tid = threadIdx.x, wave = tid >> 6, lane = tid & 63;
    int c0 = lane * 2;

    for (int g = blockIdx.x; g < N_NODES / 4; g += gridDim.x) {
        int node = g * 4 + wave;
        int s0 = offs[node], s1 = offs[node + 1];
        ushort2 sv = *(const ushort2*)(&xq[(size_t)node * CIN + c0]);  // self loop
        float2 acc;
        acc.x = bf2f(sv.x); acc.y = bf2f(sv.y);

        int nb = (s1 - s0) >> 3;
        int d = s0;
        int i0 = 0, i1 = 0, i2 = 0, i3 = 0, i4 = 0, i5 = 0, i6 = 0, i7 = 0;
        if (nb > 0) {
            i0 = csr[d + 0]; i1 = csr[d + 1]; i2 = csr[d + 2]; i3 = csr[d + 3];
            i4 = csr[d + 4]; i5 = csr[d + 5]; i6 = csr[d + 6]; i7 = csr[d + 7];
        }
        for (int t = 0; t < nb; ++t) {
            ushort2 v0 = *(const ushort2*)(&xq[(size_t)i0 * CIN + c0]);
            ushort2 v1 = *(const ushort2*)(&xq[(size_t)i1 * CIN + c0]);
            ushort2 v2 = *(const ushort2*)(&xq[(size_t)i2 * CIN + c0]);
            ushort2 v3 = *(const ushort2*)(&xq[(size_t)i3 * CIN + c0]);
            ushort2 v4 = *(const ushort2*)(&xq[(size_t)i4 * CIN + c0]);
            ushort2 v5 = *(const ushort2*)(&xq[(size_t)i5 * CIN + c0]);
            ushort2 v6 = *(const ushort2*)(&xq[(size_t)i6 * CIN + c0]);
            ushort2 v7 = *(const ushort2*)(&xq[(size_t)i7 * CIN + c0]);
            int nd = d + 8;
            int j0 = 0, j1 = 0, j2 = 0, j3 = 0, j4 = 0, j5 = 0, j6 = 0, j7 = 0;
            if (t + 1 < nb) {
                j0 = csr[nd + 0]; j1 = csr[nd + 1]; j2 = csr[nd + 2]; j3 = csr[nd + 3];
                j4 = csr[nd + 4]; j5 = csr[nd + 5]; j6 = csr[nd + 6]; j7 = csr[nd + 7];
            }
            acc.x += ((bf2f(v0.x) + bf2f(v1.x)) + (bf2f(v2.x) + bf2f(v3.x))) +
                     ((bf2f(v4.x) + bf2f(v5.x)) + (bf2f(v6.x) + bf2f(v7.x)));
            acc.y += ((bf2f(v0.y) + bf2f(v1.y)) + (bf2f(v2.y) + bf2f(v3.y))) +
                     ((bf2f(v4.y) + bf2f(v5.y)) + (bf2f(v6.y) + bf2f(v7.y)));
            d = nd;
            i0 = j0; i1 = j1; i2 = j2; i3 = j3; i4 = j4; i5 = j5; i6 = j6; i7 = j7;
        }
        for (; d + 4 <= s1; d += 4) {
            int k0 = csr[d + 0], k1 = csr[d + 1], k2 = csr[d + 2], k3 = csr[d + 3];
            ushort2 v0 = *(const ushort2*)(&xq[(size_t)k0 * CIN + c0]);
            ushort2 v1 = *(const ushort2*)(&xq[(size_t)k1 * CIN + c0]);
            ushort2 v2 = *(const ushort2*)(&xq[(size_t)k2 * CIN + c0]);
            ushort2 v3 = *(const ushort2*)(&xq[(size_t)k3 * CIN + c0]);
            acc.x += (bf2f(v0.x) + bf2f(v1.x)) + (bf2f(v2.x) + bf2f(v3.x));
            acc.y += (bf2f(v0.y) + bf2f(v1.y)) + (bf2f(v2.y) + bf2f(v3.y));
        }
        for (; d < s1; ++d) {
            int s = csr[d];
            ushort2 v = *(const ushort2*)(&xq[(size_t)s * CIN + c0]);
            acc.x += bf2f(v.x); acc.y += bf2f(v.y);
        }
        float dv = dinv[node];
        float2 o;
        o.x = acc.x * dv;
        o.y = acc.y * dv;
        *(float2*)(&u[(size_t)node * CIN + c0]) = o;
    }
}

// ---------------------------------------------------------------------------
// GEMM1 (post-agg): h1[i][c] = u[i,:] @ W1[:,c] + b1[c], fused BN stats.
// 64 rows/block, 16 rows/wave; per-block channel sums -> 1 atomic/channel.
// ---------------------------------------------------------------------------
__global__ __launch_bounds__(256) void gemm1_kernel(const float* __restrict__ u,
                                                    const float* __restrict__ W1,
                                                    const float* __restrict__ b1,
                                                    float* __restrict__ h1,
                                                    float* __restrict__ stats) {
    __shared__ float xs[64][CIN];  // 32 KB
    int tid = threadIdx.x;
    int rowBase = blockIdx.x * 64;

    const float4* ug = (const float4*)(u + (size_t)rowBase * CIN);
    float4* xsv = (float4*)(&xs[0][0]);
#pragma unroll
    for (int j = 0; j < 8; ++j) xsv[tid + j * 256] = ug[tid + j * 256];
    __syncthreads();

    int wave = tid >> 6, lane = tid & 63;
    int c0 = lane * 4;   // 64 lanes x 4 = 256 output channels
    int r0 = wave * 16;

    float4 acc[16];
#pragma unroll
    for (int r = 0; r < 16; ++r) acc[r] = make_float4(0.f, 0.f, 0.f, 0.f);

    for (int k = 0; k < CIN; k += 4) {
        float4 w0 = *(const float4*)(&W1[(k + 0) * CHID + c0]);
        float4 w1 = *(const float4*)(&W1[(k + 1) * CHID + c0]);
        float4 w2 = *(const float4*)(&W1[(k + 2) * CHID + c0]);
        float4 w3 = *(const float4*)(&W1[(k + 3) * CHID + c0]);
#pragma unroll
        for (int r = 0; r < 16; ++r) {
            float4 xv = *(const float4*)(&xs[r0 + r][k]);
            acc[r].x += xv.x * w0.x + xv.y * w1.x + xv.z * w2.x + xv.w * w3.x;
            acc[r].y += xv.x * w0.y + xv.y * w1.y + xv.z * w2.y + xv.w * w3.y;
            acc[r].z += xv.x * w0.z + xv.y * w1.z + xv.z * w2.z + xv.w * w3.z;
            acc[r].w += xv.x * w0.w + xv.y * w1.w + xv.z * w2.w + xv.w * w3.w;
        }
    }

    float4 bb = *(const float4*)(&b1[c0]);
    float4 ps = make_float4(0.f, 0.f, 0.f, 0.f);
    float4 pq = make_float4(0.f, 0.f, 0.f, 0.f);
#pragma unroll
    for (int r = 0; r < 16; ++r) {
        int row = rowBase + r0 + r;
        float4 h;
        h.x = acc[r].x + bb.x; h.y = acc[r].y + bb.y;
        h.z = acc[r].z + bb.z; h.w = acc[r].w + bb.w;
        *(float4*)(&h1[(size_t)row * CHID + c0]) = h;
        ps.x += h.x; ps.y += h.y; ps.z += h.z; ps.w += h.w;
        pq.x += h.x * h.x; pq.y += h.y * h.y; pq.z += h.z * h.z; pq.w += h.w * h.w;
    }

    __shared__ float red[4][CHID];  // 4 KB
    *(float4*)(&red[wave][c0]) = ps;
    __syncthreads();
    {
        int c = tid;  // 0..255
        float v = red[0][c] + red[1][c] + red[2][c] + red[3][c];
        atomicAdd(&stats[c], v);
    }
    __syncthreads();
    *(float4*)(&red[wave][c0]) = pq;
    __syncthreads();
    {
        int c = tid;
        float v = red[0][c] + red[1][c] + red[2][c] + red[3][c];
        atomicAdd(&stats[CHID + c], v);
    }
}

// ---------------------------------------------------------------------------
// BN prep: per-channel affine a*h+bb equivalent to BN(gamma,beta)
// ---------------------------------------------------------------------------
__global__ __launch_bounds__(256) void bnprep_kernel(const float* __restrict__ stats,
                                                     const float* __restrict__ gamma,
                                                     const float* __restrict__ beta,
                                                     float* __restrict__ ab) {
    int c = threadIdx.x;
    float mean = stats[c] * (1.0f / N_NODES);
    float var = stats[CHID + c] * (1.0f / N_NODES) - mean * mean;
    float a = gamma[c] / sqrtf(var + 1e-5f);
    ab[c] = a;
    ab[CHID + c] = beta[c] - mean * a;
}

// ---------------------------------------------------------------------------
// GEMM2: g2[i][o] = bf16( dinv[i] * ( relu(a*h1[i,:]+bb) @ W2[:,o] ) )
// affine+relu applied while staging rows into LDS; 64 rows/block.
// ---------------------------------------------------------------------------
__global__ __launch_bounds__(256) void gemm2_kernel(const float* __restrict__ h1,
                                                    const float* __restrict__ ab,
                                                    const float* __restrict__ W2,
                                                    const float* __restrict__ dinv,
                                                    unsigned short* __restrict__ g2) {
    __shared__ float xs[64][CHID];  // 64 KB
    int tid = threadIdx.x;
    int rowBase = blockIdx.x * 64;

    // (tid + j*256) & 63 == tid & 63  ->  affine coeffs are loop-invariant
    int c4 = (tid & 63) * 4;
    float4 a4 = *(const float4*)(&ab[c4]);
    float4 b4 = *(const float4*)(&ab[CHID + c4]);

    const float4* hg = (const float4*)(h1 + (size_t)rowBase * CHID);
#pragma unroll
    for (int j = 0; j < 16; ++j) {
        int idx = tid + j * 256;          // 4096 float4s = 64x256 floats
        float4 v = hg[idx];
        float4 r;
        r.x = fmaxf(v.x * a4.x + b4.x, 0.f);
        r.y = fmaxf(v.y * a4.y + b4.y, 0.f);
        r.z = fmaxf(v.z * a4.z + b4.z, 0.f);
        r.w = fmaxf(v.w * a4.w + b4.w, 0.f);
        ((float4*)(&xs[0][0]))[idx] = r;
    }
    __syncthreads();

    int wave = tid >> 6, lane = tid & 63;
    int o0 = lane * 2;  // 64 lanes x 2 = 128 outputs
    int r0 = wave * 16;

    float2 acc[16];
#pragma unroll
    for (int r = 0; r < 16; ++r) acc[r] = make_float2(0.f, 0.f);

    for (int k = 0; k < CHID; k += 4) {
        float2 w0 = *(const float2*)(&W2[(k + 0) * COUT + o0]);
        float2 w1 = *(const float2*)(&W2[(k + 1) * COUT + o0]);
        float2 w2 = *(const float2*)(&W2[(k + 2) * COUT + o0]);
        float2 w3 = *(const float2*)(&W2[(k + 3) * COUT + o0]);
#pragma unroll
        for (int r = 0; r < 16; ++r) {
            float4 xv = *(const float4*)(&xs[r0 + r][k]);
            acc[r].x += xv.x * w0.x + xv.y * w1.x + xv.z * w2.x + xv.w * w3.x;
            acc[r].y += xv.x * w0.y + xv.y * w1.y + xv.z * w2.y + xv.w * w3.y;
        }
    }

#pragma unroll
    for (int r = 0; r < 16; ++r) {
        int row = rowBase + r0 + r;
        float dv = dinv[row];
        ushort2 o;
        o.x = f2bf(acc[r].x * dv);
        o.y = f2bf(acc[r].y * dv);
        *(ushort2*)(&g2[(size_t)row * COUT + o0]) = o;  // 4B store
    }
}

// ---------------------------------------------------------------------------
// AGG2: out[i] = dinv[i]*(sum g2[src] + g2[i]) + b2
// same prefetched 8-deep pipeline (256B rows, ushort2 = 4B/lane).
// ---------------------------------------------------------------------------
__global__ __launch_bounds__(256) void agg2_kernel(const unsigned short* __restrict__ g2,
                                                   const int* __restrict__ offs,
                                                   const int* __restrict__ csr,
                                                   const float* __restrict__ dinv,
                                                   const float* __restrict__ b2,
                                                   float* __restrict__ out) {
    int tid = threadIdx.x, wave = tid >> 6, lane = tid & 63;
    int c0 = lane * 2;
    float2 b = *(const float2*)(&b2[c0]);

    for (int g = blockIdx.x; g < N_NODES / 4; g += gridDim.x) {
        int node = g * 4 + wave;
        int s0 = offs[node], s1 = offs[node + 1];
        ushort2 sv = *(const ushort2*)(&g2[(size_t)node * COUT + c0]);  // self loop
        float2 acc;
        acc.x = bf2f(sv.x); acc.y = bf2f(sv.y);

        int nb = (s1 - s0) >> 3;
        int d = s0;
        int i0 = 0, i1 = 0, i2 = 0, i3 = 0, i4 = 0, i5 = 0, i6 = 0, i7 = 0;
        if (nb > 0) {
            i0 = csr[d + 0]; i1 = csr[d + 1]; i2 = csr[d + 2]; i3 = csr[d + 3];
            i4 = csr[d + 4]; i5 = csr[d + 5]; i6 = csr[d + 6]; i7 = csr[d + 7];
        }
        for (int t = 0; t < nb; ++t) {
            ushort2 v0 = *(const ushort2*)(&g2[(size_t)i0 * COUT + c0]);
            ushort2 v1 = *(const ushort2*)(&g2[(size_t)i1 * COUT + c0]);
            ushort2 v2 = *(const ushort2*)(&g2[(size_t)i2 * COUT + c0]);
            ushort2 v3 = *(const ushort2*)(&g2[(size_t)i3 * COUT + c0]);
            ushort2 v4 = *(const ushort2*)(&g2[(size_t)i4 * COUT + c0]);
            ushort2 v5 = *(const ushort2*)(&g2[(size_t)i5 * COUT + c0]);
            ushort2 v6 = *(const ushort2*)(&g2[(size_t)i6 * COUT + c0]);
            ushort2 v7 = *(const ushort2*)(&g2[(size_t)i7 * COUT + c0]);
            int nd = d + 8;
            int j0 = 0, j1 = 0, j2 = 0, j3 = 0, j4 = 0, j5 = 0, j6 = 0, j7 = 0;
            if (t + 1 < nb) {
                j0 = csr[nd + 0]; j1 = csr[nd + 1]; j2 = csr[nd + 2]; j3 = csr[nd + 3];
                j4 = csr[nd + 4]; j5 = csr[nd + 5]; j6 = csr[nd + 6]; j7 = csr[nd + 7];
            }
            acc.x += ((bf2f(v0.x) + bf2f(v1.x)) + (bf2f(v2.x) + bf2f(v3.x))) +
                     ((bf2f(v4.x) + bf2f(v5.x)) + (bf2f(v6.x) + bf2f(v7.x)));
            acc.y += ((bf2f(v0.y) + bf2f(v1.y)) + (bf2f(v2.y) + bf2f(v3.y))) +
                     ((bf2f(v4.y) + bf2f(v5.y)) + (bf2f(v6.y) + bf2f(v7.y)));
            d = nd;
            i0 = j0; i1 = j1; i2 = j2; i3 = j3; i4 = j4; i5 = j5; i6 = j6; i7 = j7;
        }
        for (; d + 4 <= s1; d += 4) {
            int k0 = csr[d + 0], k1 = csr[d + 1], k2 = csr[d + 2], k3 = csr[d + 3];
            ushort2 v0 = *(const ushort2*)(&g2[(size_t)k0 * COUT + c0]);
            ushort2 v1 = *(const ushort2*)(&g2[(size_t)k1 * COUT + c0]);
            ushort2 v2 = *(const ushort2*)(&g2[(size_t)k2 * COUT + c0]);
            ushort2 v3 = *(const ushort2*)(&g2[(size_t)k3 * COUT + c0]);
            acc.x += (bf2f(v0.x) + bf2f(v1.x)) + (bf2f(v2.x) + bf2f(v3.x));
            acc.y += (bf2f(v0.y) + bf2f(v1.y)) + (bf2f(v2.y) + bf2f(v3.y));
        }
        for (; d < s1; ++d) {
            int s = csr[d];
            ushort2 v = *(const ushort2*)(&g2[(size_t)s * COUT + c0]);
            acc.x += bf2f(v.x); acc.y += bf2f(v.y);
        }
        float dv = dinv[node];
        float2 o;
        o.x = acc.x * dv + b.x;
        o.y = acc.y * dv + b.y;
        *(float2*)(&out[(size_t)node * COUT + c0]) = o;
    }
}

// ---------------------------------------------------------------------------
extern "C" void kernel_launch(void* const* d_in, const int* in_sizes, int n_in,
                              void* d_out, int out_size, void* d_ws, size_t ws_size,
                              hipStream_t stream) {
    const float* x     = (const float*)d_in[0];
    const int*   ei    = (const int*)d_in[1];
    const float* W1    = (const float*)d_in[2];
    const float* b1    = (const float*)d_in[3];
    const float* gamma = (const float*)d_in[4];
    const float* beta  = (const float*)d_in[5];
    const float* W2    = (const float*)d_in[6];
    const float* b2    = (const float*)d_in[7];
    float* out = (float*)d_out;

    const int* srcv = ei;            // edge_index[0]
    const int* dstv = ei + E_EDGES;  // edge_index[1]

    // workspace layout (g2 aliases xq: xq dead after aggx)
    char* ws = (char*)d_ws;
    size_t off = 0;
    auto alloc = [&](size_t bytes) -> void* {
        void* p = ws + off;
        off += (bytes + 255) & ~(size_t)255;
        return p;
    };
    int*   deg    = (int*)alloc((size_t)N_NODES * 4);
    int*   offs   = (int*)alloc((size_t)(N_NODES + 1) * 4);
    int*   rank   = (int*)alloc((size_t)E_EDGES * 4);
    float* dinv   = (float*)alloc((size_t)N_NODES * 4);
    int*   csr    = (int*)alloc((size_t)E_EDGES * 4);
    unsigned short* xq = (unsigned short*)alloc((size_t)N_NODES * CIN * 2);   // 8 MB, also g2
    float* u      = (float*)alloc((size_t)N_NODES * CIN * 4);                 // 16 MB
    float* h1     = (float*)alloc((size_t)N_NODES * CHID * 4);                // 32 MB
    float* stats  = (float*)alloc(2 * CHID * 4);
    float* ab     = (float*)alloc(2 * CHID * 4);
    unsigned short* g2 = xq;

    hipMemsetAsync(deg, 0, (size_t)N_NODES * 4, stream);
    hipMemsetAsync(stats, 0, 2 * CHID * 4, stream);

    deg_kernel<<<E_EDGES / 2 / 256, 256, 0, stream>>>(dstv, deg, rank);
    scan_kernel<<<1, 1024, 0, stream>>>(deg, offs, dinv);
    fill_kernel<<<E_EDGES / 4 / 256, 256, 0, stream>>>(srcv, dstv, rank, offs, csr);

    quantx_kernel<<<N_NODES * CIN / 4 / 256, 256, 0, stream>>>(x, dinv, xq);
    aggx_kernel<<<2048, 256, 0, stream>>>(xq, offs, csr, dinv, u);
    gemm1_kernel<<<N_NODES / 64, 256, 0, stream>>>(u, W1, b1, h1, stats);
    bnprep_kernel<<<1, 256, 0, stream>>>(stats, gamma, beta, ab);
    gemm2_kernel<<<N_NODES / 64, 256, 0, stream>>>(h1, ab, W2, dinv, g2);
    agg2_kernel<<<2048, 256, 0, stream>>>(g2, offs, csr, dinv, b2, out);
}

// Round 14
// 314.169 us; speedup vs baseline: 1.7019x; 1.0349x over previous
//
#include <hip/hip_runtime.h>
#include <hip/hip_bf16.h>
#include <math.h>

#define N_NODES 32768
#define E_EDGES 1048576
#define CIN 128
#define CHID 256
#define COUT 128

// bf16 <-> f32 helpers. Gather tables (x~, g2) stored bf16: R6 evidence says
// the agg path is bytes+requests bound, so smaller rows are the lever.
__device__ inline float bf2f(unsigned short u) {
    union { unsigned int i; float f; } c;
    c.i = ((unsigned int)u) << 16;
    return c.f;
}
__device__ inline unsigned short f2bf(float f) {
    __hip_bfloat16 h = __float2bfloat16(f);  // RNE
    return *reinterpret_cast<unsigned short*>(&h);
}

// ---------------------------------------------------------------------------
// CSR build: deg+rank count -> exclusive scan (+dinv) -> atomic-free fill
// (R10/R11: rank-from-deg removed fill's atomic->store chain; fill now ~20us)
// ---------------------------------------------------------------------------
__global__ __launch_bounds__(256) void deg_kernel(const int* __restrict__ dst,
                                                  int* __restrict__ deg,
                                                  int* __restrict__ rank) {
    int idx = blockIdx.x * blockDim.x + threadIdx.x;  // int2 index
    int2 d2 = ((const int2*)dst)[idx];
    int r0 = atomicAdd(&deg[d2.x], 1);   // 2 independent atomic chains/lane,
    int r1 = atomicAdd(&deg[d2.y], 1);   // 2048 blocks -> full occupancy
    int2 r2; r2.x = r0; r2.y = r1;
    ((int2*)rank)[idx] = r2;             // sequential 8B store
}

__global__ __launch_bounds__(1024) void scan_kernel(const int* __restrict__ deg,
                                                    int* __restrict__ offs,
                                                    float* __restrict__ dinv) {
    __shared__ int s[1024];
    int t = threadIdx.x;
    int base = t * 32;  // 1024 threads x 32 = 32768
    int ts = 0;
#pragma unroll
    for (int j = 0; j < 32; ++j) ts += deg[base + j];
    s[t] = ts;
    __syncthreads();
    // Hillis-Steele inclusive scan over 1024 thread-sums (double-barrier form)
    for (int off = 1; off < 1024; off <<= 1) {
        int v = (t >= off) ? s[t - off] : 0;
        __syncthreads();
        s[t] += v;
        __syncthreads();
    }
    int run = s[t] - ts;  // exclusive prefix for this chunk
    for (int j = 0; j < 32; ++j) {
        int idx = base + j;
        int d = deg[idx];
        offs[idx] = run;
        // reference deg includes the self-loop: indeg + 1 (always >= 1)
        dinv[idx] = 1.0f / sqrtf((float)(d + 1));
        run += d;
    }
    if (t == 1023) offs[N_NODES] = s[1023];
}

__global__ __launch_bounds__(256) void fill_kernel(const int* __restrict__ src,
                                                   const int* __restrict__ dst,
                                                   const int* __restrict__ rank,
                                                   const int* __restrict__ offs,
                                                   int* __restrict__ csr) {
    int idx = blockIdx.x * blockDim.x + threadIdx.x;  // int4 index
    int4 d4 = ((const int4*)dst)[idx];
    int4 s4 = ((const int4*)src)[idx];
    int4 r4 = ((const int4*)rank)[idx];
    // offs is 128KB -> L2-resident; gathers cheap. Stores fire-and-forget.
    csr[offs[d4.x] + r4.x] = s4.x;
    csr[offs[d4.y] + r4.y] = s4.y;
    csr[offs[d4.z] + r4.z] = s4.z;
    csr[offs[d4.w] + r4.w] = s4.w;
}

// ---------------------------------------------------------------------------
// QUANTX: xq[i][c] = bf16( x[i][c] * dinv[i] )   (256B rows for the gather)
// ---------------------------------------------------------------------------
__global__ __launch_bounds__(256) void quantx_kernel(const float* __restrict__ x,
                                                     const float* __restrict__ dinv,
                                                     unsigned short* __restrict__ xq) {
    int idx = blockIdx.x * 256 + threadIdx.x;  // float4 index; N*CIN/4 total
    int row = idx >> 5;                        // 32 float4s per 128-ch row
    float dv = dinv[row];
    float4 v = ((const float4*)x)[idx];
    ushort4 o;
    o.x = f2bf(v.x * dv); o.y = f2bf(v.y * dv);
    o.z = f2bf(v.z * dv); o.w = f2bf(v.w * dv);
    ((ushort4*)xq)[idx] = o;
}

// ---------------------------------------------------------------------------
// AGGX: u[i] = dinv[i]*(sum_{e:dst=i} xq[src] + xq[i])      (layer-1 agg in
// the 128-dim INPUT space). 8-deep gather pipeline, f32 accum.
// ---------------------------------------------------------------------------
__global__ __launch_bounds__(256) void aggx_kernel(const unsigned short* __restrict__ xq,
                                                   const int* __restrict__ offs,
                                                   const int* __restrict__ csr,
                                                   const float* __restrict__ dinv,
                                                   float* __restrict__ u) {
    int tid = threadIdx.x, wave = tid >> 6, lane = tid & 63;
    int c0 = lane * 2;

    for (int g = blockIdx.x; g < N_NODES / 4; g += gridDim.x) {
        int node = g * 4 + wave;
        int s0 = offs[node], s1 = offs[node + 1];
        ushort2 sv = *(const ushort2*)(&xq[(size_t)node * CIN + c0]);  // self loop
        float2 acc;
        acc.x = bf2f(sv.x); acc.y = bf2f(sv.y);

        int nb = (s1 - s0) >> 3;
        int d = s0;
        int i0 = 0, i1 = 0, i2 = 0, i3 = 0, i4 = 0, i5 = 0, i6 = 0, i7 = 0;
        if (nb > 0) {
            i0 = csr[d + 0]; i1 = csr[d + 1]; i2 = csr[d + 2]; i3 = csr[d + 3];
            i4 = csr[d + 4]; i5 = csr[d + 5]; i6 = csr[d + 6]; i7 = csr[d + 7];
        }
        for (int t = 0; t < nb; ++t) {
            ushort2 v0 = *(const ushort2*)(&xq[(size_t)i0 * CIN + c0]);
            ushort2 v1 = *(const ushort2*)(&xq[(size_t)i1 * CIN + c0]);
            ushort2 v2 = *(const ushort2*)(&xq[(size_t)i2 * CIN + c0]);
            ushort2 v3 = *(const ushort2*)(&xq[(size_t)i3 * CIN + c0]);
            ushort2 v4 = *(const ushort2*)(&xq[(size_t)i4 * CIN + c0]);
            ushort2 v5 = *(const ushort2*)(&xq[(size_t)i5 * CIN + c0]);
            ushort2 v6 = *(const ushort2*)(&xq[(size_t)i6 * CIN + c0]);
            ushort2 v7 = *(const ushort2*)(&xq[(size_t)i7 * CIN + c0]);
            int nd = d + 8;
            int j0 = 0, j1 = 0, j2 = 0, j3 = 0, j4 = 0, j5 = 0, j6 = 0, j7 = 0;
            if (t + 1 < nb) {
                j0 = csr[nd + 0]; j1 = csr[nd + 1]; j2 = csr[nd + 2]; j3 = csr[nd + 3];
                j4 = csr[nd + 4]; j5 = csr[nd + 5]; j6 = csr[nd + 6]; j7 = csr[nd + 7];
            }
            acc.x += ((bf2f(v0.x) + bf2f(v1.x)) + (bf2f(v2.x) + bf2f(v3.x))) +
                     ((bf2f(v4.x) + bf2f(v5.x)) + (bf2f(v6.x) + bf2f(v7.x)));
            acc.y += ((bf2f(v0.y) + bf2f(v1.y)) + (bf2f(v2.y) + bf2f(v3.y))) +
                     ((bf2f(v4.y) + bf2f(v5.y)) + (bf2f(v6.y) + bf2f(v7.y)));
            d = nd;
            i0 = j0; i1 = j1; i2 = j2; i3 = j3; i4 = j4; i5 = j5; i6 = j6; i7 = j7;
        }
        for (; d + 4 <= s1; d += 4) {
            int k0 = csr[d + 0], k1 = csr[d + 1], k2 = csr[d + 2], k3 = csr[d + 3];
            ushort2 v0 = *(const ushort2*)(&xq[(size_t)k0 * CIN + c0]);
            ushort2 v1 = *(const ushort2*)(&xq[(size_t)k1 * CIN + c0]);
            ushort2 v2 = *(const ushort2*)(&xq[(size_t)k2 * CIN + c0]);
            ushort2 v3 = *(const ushort2*)(&xq[(size_t)k3 * CIN + c0]);
            acc.x += (bf2f(v0.x) + bf2f(v1.x)) + (bf2f(v2.x) + bf2f(v3.x));
            acc.y += (bf2f(v0.y) + bf2f(v1.y)) + (bf2f(v2.y) + bf2f(v3.y));
        }
        for (; d < s1; ++d) {
            int s = csr[d];
            ushort2 v = *(const ushort2*)(&xq[(size_t)s * CIN + c0]);
            acc.x += bf2f(v.x); acc.y += bf2f(v.y);
        }
        float dv = dinv[node];
        float2 o;
        o.x = acc.x * dv;
        o.y = acc.y * dv;
        *(float2*)(&u[(size_t)node * CIN + c0]) = o;
    }
}

// ---------------------------------------------------------------------------
// GEMM1 (post-agg): h1[i][c] = u[i,:] @ W1[:,c] + b1[c], fused BN stats.
// R11 evidence: 64-row blocks -> 512 blocks -> 18.7% occupancy, VALUBusy 28%,
// latency-bound on dependent W loads. Fix: 32 rows/block (1024 blocks, ~50%
// occupancy) + software-pipelined W prefetch (load k+4 before computing k).
// ---------------------------------------------------------------------------
__global__ __launch_bounds__(256) void gemm1_kernel(const float* __restrict__ u,
                                                    const float* __restrict__ W1,
                                                    const float* __restrict__ b1,
                                                    float* __restrict__ h1,
                                                    float* __restrict__ stats) {
    __shared__ float xs[32][CIN];  // 16 KB
    int tid = threadIdx.x;
    int rowBase = blockIdx.x * 32;

    const float4* ug = (const float4*)(u + (size_t)rowBase * CIN);
    float4* xsv = (float4*)(&xs[0][0]);
#pragma unroll
    for (int j = 0; j < 4; ++j) xsv[tid + j * 256] = ug[tid + j * 256];
    __syncthreads();

    int wave = tid >> 6, lane = tid & 63;
    int c0 = lane * 4;   // 64 lanes x 4 = 256 output channels
    int r0 = wave * 8;   // 8 rows/wave

    float4 acc[8];
#pragma unroll
    for (int r = 0; r < 8; ++r) acc[r] = make_float4(0.f, 0.f, 0.f, 0.f);

    // software-pipelined W loads: wa = current k-step, wb = prefetched k+4
    float4 wa0 = *(const float4*)(&W1[0 * CHID + c0]);
    float4 wa1 = *(const float4*)(&W1[1 * CHID + c0]);
    float4 wa2 = *(const float4*)(&W1[2 * CHID + c0]);
    float4 wa3 = *(const float4*)(&W1[3 * CHID + c0]);

    for (int k = 0; k < CIN - 4; k += 4) {
        float4 wb0 = *(const float4*)(&W1[(k + 4) * CHID + c0]);
        float4 wb1 = *(const float4*)(&W1[(k + 5) * CHID + c0]);
        float4 wb2 = *(const float4*)(&W1[(k + 6) * CHID + c0]);
        float4 wb3 = *(const float4*)(&W1[(k + 7) * CHID + c0]);
#pragma unroll
        for (int r = 0; r < 8; ++r) {
            float4 xv = *(const float4*)(&xs[r0 + r][k]);
            acc[r].x += xv.x * wa0.x + xv.y * wa1.x + xv.z * wa2.x + xv.w * wa3.x;
            acc[r].y += xv.x * wa0.y + xv.y * wa1.y + xv.z * wa2.y + xv.w * wa3.y;
            acc[r].z += xv.x * wa0.z + xv.y * wa1.z + xv.z * wa2.z + xv.w * wa3.z;
            acc[r].w += xv.x * wa0.w + xv.y * wa1.w + xv.z * wa2.w + xv.w * wa3.w;
        }
        wa0 = wb0; wa1 = wb1; wa2 = wb2; wa3 = wb3;
    }
    {   // final k-step (CIN-4) with already-loaded wa*
        int k = CIN - 4;
#pragma unroll
        for (int r = 0; r < 8; ++r) {
            float4 xv = *(const float4*)(&xs[r0 + r][k]);
            acc[r].x += xv.x * wa0.x + xv.y * wa1.x + xv.z * wa2.x + xv.w * wa3.x;
            acc[r].y += xv.x * wa0.y + xv.y * wa1.y + xv.z * wa2.y + xv.w * wa3.y;
            acc[r].z += xv.x * wa0.z + xv.y * wa1.z + xv.z * wa2.z + xv.w * wa3.z;
            acc[r].w += xv.x * wa0.w + xv.y * wa1.w + xv.z * wa2.w + xv.w * wa3.w;
        }
    }

    float4 bb = *(const float4*)(&b1[c0]);
    float4 ps = make_float4(0.f, 0.f, 0.f, 0.f);
    float4 pq = make_float4(0.f, 0.f, 0.f, 0.f);
#pragma unroll
    for (int r = 0; r < 8; ++r) {
        int row = rowBase + r0 + r;
        float4 h;
        h.x = acc[r].x + bb.x; h.y = acc[r].y + bb.y;
        h.z = acc[r].z + bb.z; h.w = acc[r].w + bb.w;
        *(float4*)(&h1[(size_t)row * CHID + c0]) = h;
        ps.x += h.x; ps.y += h.y; ps.z += h.z; ps.w += h.w;
        pq.x += h.x * h.x; pq.y += h.y * h.y; pq.z += h.z * h.z; pq.w += h.w * h.w;
    }

    __shared__ float red[4][CHID];  // 4 KB
    *(float4*)(&red[wave][c0]) = ps;
    __syncthreads();
    {
        int c = tid;  // 0..255
        float v = red[0][c] + red[1][c] + red[2][c] + red[3][c];
        atomicAdd(&stats[c], v);
    }
    __syncthreads();
    *(float4*)(&red[wave][c0]) = pq;
    __syncthreads();
    {
        int c = tid;
        float v = red[0][c] + red[1][c] + red[2][c] + red[3][c];
        atomicAdd(&stats[CHID + c], v);
    }
}

// ---------------------------------------------------------------------------
// BN prep: per-channel affine a*h+bb equivalent to BN(gamma,beta)
// ---------------------------------------------------------------------------
__global__ __launch_bounds__(256) void bnprep_kernel(const float* __restrict__ stats,
                                                     const float* __restrict__ gamma,
                                                     const float* __restrict__ beta,
                                                     float* __restrict__ ab) {
    int c = threadIdx.x;
    float mean = stats[c] * (1.0f / N_NODES);
    float var = stats[CHID + c] * (1.0f / N_NODES) - mean * mean;
    float a = gamma[c] / sqrtf(var + 1e-5f);
    ab[c] = a;
    ab[CHID + c] = beta[c] - mean * a;
}

// ---------------------------------------------------------------------------
// GEMM2: g2[i][o] = bf16( dinv[i] * ( relu(a*h1[i,:]+bb) @ W2[:,o] ) )
// same occupancy+prefetch treatment: 32 rows/block (32KB LDS, 1024 blocks).
// ---------------------------------------------------------------------------
__global__ __launch_bounds__(256) void gemm2_kernel(const float* __restrict__ h1,
                                                    const float* __restrict__ ab,
                                                    const float* __restrict__ W2,
                                                    const float* __restrict__ dinv,
                                                    unsigned short* __restrict__ g2) {
    __shared__ float xs[32][CHID];  // 32 KB
    int tid = threadIdx.x;
    int rowBase = blockIdx.x * 32;

    // (tid + j*256) & 63 == tid & 63  ->  affine coeffs are loop-invariant
    int c4 = (tid & 63) * 4;
    float4 a4 = *(const float4*)(&ab[c4]);
    float4 b4 = *(const float4*)(&ab[CHID + c4]);

    const float4* hg = (const float4*)(h1 + (size_t)rowBase * CHID);
#pragma unroll
    for (int j = 0; j < 8; ++j) {
        int idx = tid + j * 256;          // 2048 float4s = 32x256 floats
        float4 v = hg[idx];
        float4 r;
        r.x = fmaxf(v.x * a4.x + b4.x, 0.f);
        r.y = fmaxf(v.y * a4.y + b4.y, 0.f);
        r.z = fmaxf(v.z * a4.z + b4.z, 0.f);
        r.w = fmaxf(v.w * a4.w + b4.w, 0.f);
        ((float4*)(&xs[0][0]))[idx] = r;
    }
    __syncthreads();

    int wave = tid >> 6, lane = tid & 63;
    int o0 = lane * 2;  // 64 lanes x 2 = 128 outputs
    int r0 = wave * 8;  // 8 rows/wave

    float2 acc[8];
#pragma unroll
    for (int r = 0; r < 8; ++r) acc[r] = make_float2(0.f, 0.f);

    float2 wa0 = *(const float2*)(&W2[0 * COUT + o0]);
    float2 wa1 = *(const float2*)(&W2[1 * COUT + o0]);
    float2 wa2 = *(const float2*)(&W2[2 * COUT + o0]);
    float2 wa3 = *(const float2*)(&W2[3 * COUT + o0]);

    for (int k = 0; k < CHID - 4; k += 4) {
        float2 wb0 = *(const float2*)(&W2[(k + 4) * COUT + o0]);
        float2 wb1 = *(const float2*)(&W2[(k + 5) * COUT + o0]);
        float2 wb2 = *(const float2*)(&W2[(k + 6) * COUT + o0]);
        float2 wb3 = *(const float2*)(&W2[(k + 7) * COUT + o0]);
#pragma unroll
        for (int r = 0; r < 8; ++r) {
            float4 xv = *(const float4*)(&xs[r0 + r][k]);
            acc[r].x += xv.x * wa0.x + xv.y * wa1.x + xv.z * wa2.x + xv.w * wa3.x;
            acc[r].y += xv.x * wa0.y + xv.y * wa1.y + xv.z * wa2.y + xv.w * wa3.y;
        }
        wa0 = wb0; wa1 = wb1; wa2 = wb2; wa3 = wb3;
    }
    {
        int k = CHID - 4;
#pragma unroll
        for (int r = 0; r < 8; ++r) {
            float4 xv = *(const float4*)(&xs[r0 + r][k]);
            acc[r].x += xv.x * wa0.x + xv.y * wa1.x + xv.z * wa2.x + xv.w * wa3.x;
            acc[r].y += xv.x * wa0.y + xv.y * wa1.y + xv.z * wa2.y + xv.w * wa3.y;
        }
    }

#pragma unroll
    for (int r = 0; r < 8; ++r) {
        int row = rowBase + r0 + r;
        float dv = dinv[row];
        ushort2 o;
        o.x = f2bf(acc[r].x * dv);
        o.y = f2bf(acc[r].y * dv);
        *(ushort2*)(&g2[(size_t)row * COUT + o0]) = o;  // 4B store
    }
}

// ---------------------------------------------------------------------------
// AGG2: out[i] = dinv[i]*(sum g2[src] + g2[i]) + b2
// same prefetched 8-deep pipeline (256B rows, ushort2 = 4B/lane).
// ---------------------------------------------------------------------------
__global__ __launch_bounds__(256) void agg2_kernel(const unsigned short* __restrict__ g2,
                                                   const int* __restrict__ offs,
                                                   const int* __restrict__ csr,
                                                   const float* __restrict__ dinv,
                                                   const float* __restrict__ b2,
                                                   float* __restrict__ out) {
    int tid = threadIdx.x, wave = tid >> 6, lane = tid & 63;
    int c0 = lane * 2;
    float2 b = *(const float2*)(&b2[c0]);

    for (int g = blockIdx.x; g < N_NODES / 4; g += gridDim.x) {
        int node = g * 4 + wave;
        int s0 = offs[node], s1 = offs[node + 1];
        ushort2 sv = *(const ushort2*)(&g2[(size_t)node * COUT + c0]);  // self loop
        float2 acc;
        acc.x = bf2f(sv.x); acc.y = bf2f(sv.y);

        int nb = (s1 - s0) >> 3;
        int d = s0;
        int i0 = 0, i1 = 0, i2 = 0, i3 = 0, i4 = 0, i5 = 0, i6 = 0, i7 = 0;
        if (nb > 0) {
            i0 = csr[d + 0]; i1 = csr[d + 1]; i2 = csr[d + 2]; i3 = csr[d + 3];
            i4 = csr[d + 4]; i5 = csr[d + 5]; i6 = csr[d + 6]; i7 = csr[d + 7];
        }
        for (int t = 0; t < nb; ++t) {
            ushort2 v0 = *(const ushort2*)(&g2[(size_t)i0 * COUT + c0]);
            ushort2 v1 = *(const ushort2*)(&g2[(size_t)i1 * COUT + c0]);
            ushort2 v2 = *(const ushort2*)(&g2[(size_t)i2 * COUT + c0]);
            ushort2 v3 = *(const ushort2*)(&g2[(size_t)i3 * COUT + c0]);
            ushort2 v4 = *(const ushort2*)(&g2[(size_t)i4 * COUT + c0]);
            ushort2 v5 = *(const ushort2*)(&g2[(size_t)i5 * COUT + c0]);
            ushort2 v6 = *(const ushort2*)(&g2[(size_t)i6 * COUT + c0]);
            ushort2 v7 = *(const ushort2*)(&g2[(size_t)i7 * COUT + c0]);
            int nd = d + 8;
            int j0 = 0, j1 = 0, j2 = 0, j3 = 0, j4 = 0, j5 = 0, j6 = 0, j7 = 0;
            if (t + 1 < nb) {
                j0 = csr[nd + 0]; j1 = csr[nd + 1]; j2 = csr[nd + 2]; j3 = csr[nd + 3];
                j4 = csr[nd + 4]; j5 = csr[nd + 5]; j6 = csr[nd + 6]; j7 = csr[nd + 7];
            }
            acc.x += ((bf2f(v0.x) + bf2f(v1.x)) + (bf2f(v2.x) + bf2f(v3.x))) +
                     ((bf2f(v4.x) + bf2f(v5.x)) + (bf2f(v6.x) + bf2f(v7.x)));
            acc.y += ((bf2f(v0.y) + bf2f(v1.y)) + (bf2f(v2.y) + bf2f(v3.y))) +
                     ((bf2f(v4.y) + bf2f(v5.y)) + (bf2f(v6.y) + bf2f(v7.y)));
            d = nd;
            i0 = j0; i1 = j1; i2 = j2; i3 = j3; i4 = j4; i5 = j5; i6 = j6; i7 = j7;
        }
        for (; d + 4 <= s1; d += 4) {
            int k0 = csr[d + 0], k1 = csr[d + 1], k2 = csr[d + 2], k3 = csr[d + 3];
            ushort2 v0 = *(const ushort2*)(&g2[(size_t)k0 * COUT + c0]);
            ushort2 v1 = *(const ushort2*)(&g2[(size_t)k1 * COUT + c0]);
            ushort2 v2 = *(const ushort2*)(&g2[(size_t)k2 * COUT + c0]);
            ushort2 v3 = *(const ushort2*)(&g2[(size_t)k3 * COUT + c0]);
            acc.x += (bf2f(v0.x) + bf2f(v1.x)) + (bf2f(v2.x) + bf2f(v3.x));
            acc.y += (bf2f(v0.y) + bf2f(v1.y)) + (bf2f(v2.y) + bf2f(v3.y));
        }
        for (; d < s1; ++d) {
            int s = csr[d];
            ushort2 v = *(const ushort2*)(&g2[(size_t)s * COUT + c0]);
            acc.x += bf2f(v.x); acc.y += bf2f(v.y);
        }
        float dv = dinv[node];
        float2 o;
        o.x = acc.x * dv + b.x;
        o.y = acc.y * dv + b.y;
        *(float2*)(&out[(size_t)node * COUT + c0]) = o;
    }
}

// ---------------------------------------------------------------------------
extern "C" void kernel_launch(void* const* d_in, const int* in_sizes, int n_in,
                              void* d_out, int out_size, void* d_ws, size_t ws_size,
                              hipStream_t stream) {
    const float* x     = (const float*)d_in[0];
    const int*   ei    = (const int*)d_in[1];
    const float* W1    = (const float*)d_in[2];
    const float* b1    = (const float*)d_in[3];
    const float* gamma = (const float*)d_in[4];
    const float* beta  = (const float*)d_in[5];
    const float* W2    = (const float*)d_in[6];
    const float* b2    = (const float*)d_in[7];
    float* out = (float*)d_out;

    const int* srcv = ei;            // edge_index[0]
    const int* dstv = ei + E_EDGES;  // edge_index[1]

    // workspace layout (g2 aliases xq: xq dead after aggx)
    char* ws = (char*)d_ws;
    size_t off = 0;
    auto alloc = [&](size_t bytes) -> void* {
        void* p = ws + off;
        off += (bytes + 255) & ~(size_t)255;
        return p;
    };
    int*   deg    = (int*)alloc((size_t)N_NODES * 4);
    int*   offs   = (int*)alloc((size_t)(N_NODES + 1) * 4);
    int*   rank   = (int*)alloc((size_t)E_EDGES * 4);
    float* dinv   = (float*)alloc((size_t)N_NODES * 4);
    int*   csr    = (int*)alloc((size_t)E_EDGES * 4);
    unsigned short* xq = (unsigned short*)alloc((size_t)N_NODES * CIN * 2);   // 8 MB, also g2
    float* u      = (float*)alloc((size_t)N_NODES * CIN * 4);                 // 16 MB
    float* h1     = (float*)alloc((size_t)N_NODES * CHID * 4);                // 32 MB
    float* stats  = (float*)alloc(2 * CHID * 4);
    float* ab     = (float*)alloc(2 * CHID * 4);
    unsigned short* g2 = xq;

    hipMemsetAsync(deg, 0, (size_t)N_NODES * 4, stream);
    hipMemsetAsync(stats, 0, 2 * CHID * 4, stream);

    deg_kernel<<<E_EDGES / 2 / 256, 256, 0, stream>>>(dstv, deg, rank);
    scan_kernel<<<1, 1024, 0, stream>>>(deg, offs, dinv);
    fill_kernel<<<E_EDGES / 4 / 256, 256, 0, stream>>>(srcv, dstv, rank, offs, csr);

    quantx_kernel<<<N_NODES * CIN / 4 / 256, 256, 0, stream>>>(x, dinv, xq);
    aggx_kernel<<<2048, 256, 0, stream>>>(xq, offs, csr, dinv, u);
    gemm1_kernel<<<N_NODES / 32, 256, 0, stream>>>(u, W1, b1, h1, stats);
    bnprep_kernel<<<1, 256, 0, stream>>>(stats, gamma, beta, ab);
    gemm2_kernel<<<N_NODES / 32, 256, 0, stream>>>(h1, ab, W2, dinv, g2);
    agg2_kernel<<<2048, 256, 0, stream>>>(g2, offs, csr, dinv, b2, out);
}

// Round 15
// 288.363 us; speedup vs baseline: 1.8542x; 1.0895x over previous
//
#include <hip/hip_runtime.h>
#include <hip/hip_bf16.h>
#include <math.h>

#define N_NODES 32768
#define E_EDGES 1048576
#define CIN 128
#define CHID 256
#define COUT 128

typedef __attribute__((ext_vector_type(8))) short bf16x8;
typedef __attribute__((ext_vector_type(4))) float f32x4;

// bf16 <-> f32 helpers. Gather tables + GEMM operands stored bf16.
__device__ inline float bf2f(unsigned short u) {
    union { unsigned int i; float f; } c;
    c.i = ((unsigned int)u) << 16;
    return c.f;
}
__device__ inline unsigned short f2bf(float f) {
    __hip_bfloat16 h = __float2bfloat16(f);  // RNE
    return *reinterpret_cast<unsigned short*>(&h);
}

// ---------------------------------------------------------------------------
// CSR build: deg+rank count -> exclusive scan (+dinv) -> atomic-free fill
// ---------------------------------------------------------------------------
__global__ __launch_bounds__(256) void deg_kernel(const int* __restrict__ dst,
                                                  int* __restrict__ deg,
                                                  int* __restrict__ rank) {
    int idx = blockIdx.x * blockDim.x + threadIdx.x;  // int2 index
    int2 d2 = ((const int2*)dst)[idx];
    int r0 = atomicAdd(&deg[d2.x], 1);
    int r1 = atomicAdd(&deg[d2.y], 1);
    int2 r2; r2.x = r0; r2.y = r1;
    ((int2*)rank)[idx] = r2;
}

__global__ __launch_bounds__(1024) void scan_kernel(const int* __restrict__ deg,
                                                    int* __restrict__ offs,
                                                    float* __restrict__ dinv) {
    __shared__ int s[1024];
    int t = threadIdx.x;
    int base = t * 32;
    int ts = 0;
#pragma unroll
    for (int j = 0; j < 32; ++j) ts += deg[base + j];
    s[t] = ts;
    __syncthreads();
    for (int off = 1; off < 1024; off <<= 1) {
        int v = (t >= off) ? s[t - off] : 0;
        __syncthreads();
        s[t] += v;
        __syncthreads();
    }
    int run = s[t] - ts;
    for (int j = 0; j < 32; ++j) {
        int idx = base + j;
        int d = deg[idx];
        offs[idx] = run;
        dinv[idx] = 1.0f / sqrtf((float)(d + 1));  // deg includes self-loop
        run += d;
    }
    if (t == 1023) offs[N_NODES] = s[1023];
}

__global__ __launch_bounds__(256) void fill_kernel(const int* __restrict__ src,
                                                   const int* __restrict__ dst,
                                                   const int* __restrict__ rank,
                                                   const int* __restrict__ offs,
                                                   int* __restrict__ csr) {
    int idx = blockIdx.x * blockDim.x + threadIdx.x;  // int4 index
    int4 d4 = ((const int4*)dst)[idx];
    int4 s4 = ((const int4*)src)[idx];
    int4 r4 = ((const int4*)rank)[idx];
    csr[offs[d4.x] + r4.x] = s4.x;
    csr[offs[d4.y] + r4.y] = s4.y;
    csr[offs[d4.z] + r4.z] = s4.z;
    csr[offs[d4.w] + r4.w] = s4.w;
}

// ---------------------------------------------------------------------------
// QUANTX: xq[i][c] = bf16( x[i][c] * dinv[i] )
// ---------------------------------------------------------------------------
__global__ __launch_bounds__(256) void quantx_kernel(const float* __restrict__ x,
                                                     const float* __restrict__ dinv,
                                                     unsigned short* __restrict__ xq) {
    int idx = blockIdx.x * 256 + threadIdx.x;
    int row = idx >> 5;
    float dv = dinv[row];
    float4 v = ((const float4*)x)[idx];
    ushort4 o;
    o.x = f2bf(v.x * dv); o.y = f2bf(v.y * dv);
    o.z = f2bf(v.z * dv); o.w = f2bf(v.w * dv);
    ((ushort4*)xq)[idx] = o;
}

// ---------------------------------------------------------------------------
// QUANTW: pre-transpose + bf16-quantize weights so MFMA B-fragments are
// contiguous 16B loads. W1T[c][k]=W1[k][c] (256x128), W2T[o][k]=W2[k][o]
// (128x256). 64K elements total, L2-resident, ~2us.
// ---------------------------------------------------------------------------
__global__ __launch_bounds__(256) void quantw_kernel(const float* __restrict__ W1,
                                                     const float* __restrict__ W2,
                                                     unsigned short* __restrict__ w1t,
                                                     unsigned short* __restrict__ w2t) {
    int idx = blockIdx.x * 256 + threadIdx.x;  // 0..65535
    if (idx < CHID * CIN) {
        int c = idx >> 7, k = idx & 127;       // W1T[c][k] = W1[k][c]
        w1t[idx] = f2bf(W1[k * CHID + c]);
    } else {
        int j = idx - CHID * CIN;
        int o = j >> 8, k = j & 255;           // W2T[o][k] = W2[k][o]
        w2t[j] = f2bf(W2[k * COUT + o]);
    }
}

// ---------------------------------------------------------------------------
// AGGX: uq[i] = bf16( dinv[i]*(sum_{e:dst=i} xq[src] + xq[i]) )
// 8-deep gather pipeline, f32 accum, bf16 out (feeds gemm1's MFMA A-side).
// ---------------------------------------------------------------------------
__global__ __launch_bounds__(256) void aggx_kernel(const unsigned short* __restrict__ xq,
                                                   const int* __restrict__ offs,
                                                   const int* __restrict__ csr,
                                                   const float* __restrict__ dinv,
                                                   unsigned short* __restrict__ uq) {
    int tid = threadIdx.x, wave = tid >> 6, lane = tid & 63;
    int c0 = lane * 2;

    for (int g = blockIdx.x; g < N_NODES / 4; g += gridDim.x) {
        int node = g * 4 + wave;
        int s0 = offs[node], s1 = offs[node + 1];
        ushort2 sv = *(const ushort2*)(&xq[(size_t)node * CIN + c0]);  // self loop
        float2 acc;
        acc.x = bf2f(sv.x); acc.y = bf2f(sv.y);

        int nb = (s1 - s0) >> 3;
        int d = s0;
        int i0 = 0, i1 = 0, i2 = 0, i3 = 0, i4 = 0, i5 = 0, i6 = 0, i7 = 0;
        if (nb > 0) {
            i0 = csr[d + 0]; i1 = csr[d + 1]; i2 = csr[d + 2]; i3 = csr[d + 3];
            i4 = csr[d + 4]; i5 = csr[d + 5]; i6 = csr[d + 6]; i7 = csr[d + 7];
        }
        for (int t = 0; t < nb; ++t) {
            ushort2 v0 = *(const ushort2*)(&xq[(size_t)i0 * CIN + c0]);
            ushort2 v1 = *(const ushort2*)(&xq[(size_t)i1 * CIN + c0]);
            ushort2 v2 = *(const ushort2*)(&xq[(size_t)i2 * CIN + c0]);
            ushort2 v3 = *(const ushort2*)(&xq[(size_t)i3 * CIN + c0]);
            ushort2 v4 = *(const ushort2*)(&xq[(size_t)i4 * CIN + c0]);
            ushort2 v5 = *(const ushort2*)(&xq[(size_t)i5 * CIN + c0]);
            ushort2 v6 = *(const ushort2*)(&xq[(size_t)i6 * CIN + c0]);
            ushort2 v7 = *(const ushort2*)(&xq[(size_t)i7 * CIN + c0]);
            int nd = d + 8;
            int j0 = 0, j1 = 0, j2 = 0, j3 = 0, j4 = 0, j5 = 0, j6 = 0, j7 = 0;
            if (t + 1 < nb) {
                j0 = csr[nd + 0]; j1 = csr[nd + 1]; j2 = csr[nd + 2]; j3 = csr[nd + 3];
                j4 = csr[nd + 4]; j5 = csr[nd + 5]; j6 = csr[nd + 6]; j7 = csr[nd + 7];
            }
            acc.x += ((bf2f(v0.x) + bf2f(v1.x)) + (bf2f(v2.x) + bf2f(v3.x))) +
                     ((bf2f(v4.x) + bf2f(v5.x)) + (bf2f(v6.x) + bf2f(v7.x)));
            acc.y += ((bf2f(v0.y) + bf2f(v1.y)) + (bf2f(v2.y) + bf2f(v3.y))) +
                     ((bf2f(v4.y) + bf2f(v5.y)) + (bf2f(v6.y) + bf2f(v7.y)));
            d = nd;
            i0 = j0; i1 = j1; i2 = j2; i3 = j3; i4 = j4; i5 = j5; i6 = j6; i7 = j7;
        }
        for (; d + 4 <= s1; d += 4) {
            int k0 = csr[d + 0], k1 = csr[d + 1], k2 = csr[d + 2], k3 = csr[d + 3];
            ushort2 v0 = *(const ushort2*)(&xq[(size_t)k0 * CIN + c0]);
            ushort2 v1 = *(const ushort2*)(&xq[(size_t)k1 * CIN + c0]);
            ushort2 v2 = *(const ushort2*)(&xq[(size_t)k2 * CIN + c0]);
            ushort2 v3 = *(const ushort2*)(&xq[(size_t)k3 * CIN + c0]);
            acc.x += (bf2f(v0.x) + bf2f(v1.x)) + (bf2f(v2.x) + bf2f(v3.x));
            acc.y += (bf2f(v0.y) + bf2f(v1.y)) + (bf2f(v2.y) + bf2f(v3.y));
        }
        for (; d < s1; ++d) {
            int s = csr[d];
            ushort2 v = *(const ushort2*)(&xq[(size_t)s * CIN + c0]);
            acc.x += bf2f(v.x); acc.y += bf2f(v.y);
        }
        float dv = dinv[node];
        ushort2 o;
        o.x = f2bf(acc.x * dv);
        o.y = f2bf(acc.y * dv);
        *(ushort2*)(&uq[(size_t)node * CIN + c0]) = o;
    }
}

// ---------------------------------------------------------------------------
// GEMM1 (MFMA): h1[m][c] = (uq @ W1)[m][c] + b1[c], fused BN stats.
// R14 evidence: vector-FMA gemm1 plateaued at ~50us (43TF, 27% of f32 peak,
// occupancy-capped). MFMA bf16 16x16x32: per wave 16 rows x 256 ch,
// 4 k-steps x 16 MFMA. Fragment map (m89-verified C/D): A: lane holds
// A[l&15][(l>>4)*8+e]; B: B[(l>>4)*8+e][l&15]; D: D[(l>>4)*4+r][l&15].
// ---------------------------------------------------------------------------
__global__ __launch_bounds__(256) void gemm1_kernel(const unsigned short* __restrict__ uq,
                                                    const unsigned short* __restrict__ w1t,
                                                    const float* __restrict__ b1,
                                                    float* __restrict__ h1,
                                                    float* __restrict__ stats) {
    int tid = threadIdx.x, wv = tid >> 6, l = tid & 63;
    int rowBase = blockIdx.x * 64 + wv * 16;
    int lm = l & 15, lg = l >> 4;

    // A-fragments: uq[rowBase+lm][ks*32 + lg*8 + e], 16B each, all 4 k-steps
    const unsigned short* up = uq + (size_t)(rowBase + lm) * CIN + lg * 8;
    bf16x8 afr0 = *(const bf16x8*)(up + 0);
    bf16x8 afr1 = *(const bf16x8*)(up + 32);
    bf16x8 afr2 = *(const bf16x8*)(up + 64);
    bf16x8 afr3 = *(const bf16x8*)(up + 96);

    f32x4 acc[16];
#pragma unroll
    for (int t = 0; t < 16; ++t) acc[t] = (f32x4){0.f, 0.f, 0.f, 0.f};

    // B[k][n] = W1[k][t*16+n] = W1T[t*16+n][k]; lane reads 8 consecutive k.
    const unsigned short* wb = w1t + (size_t)lm * CIN + lg * 8;
#pragma unroll
    for (int t = 0; t < 16; ++t) {
        const unsigned short* wt = wb + (size_t)t * 16 * CIN;
        bf16x8 b0 = *(const bf16x8*)(wt + 0);
        bf16x8 b1f = *(const bf16x8*)(wt + 32);
        bf16x8 b2 = *(const bf16x8*)(wt + 64);
        bf16x8 b3 = *(const bf16x8*)(wt + 96);
        acc[t] = __builtin_amdgcn_mfma_f32_16x16x32_bf16(afr0, b0, acc[t], 0, 0, 0);
        acc[t] = __builtin_amdgcn_mfma_f32_16x16x32_bf16(afr1, b1f, acc[t], 0, 0, 0);
        acc[t] = __builtin_amdgcn_mfma_f32_16x16x32_bf16(afr2, b2, acc[t], 0, 0, 0);
        acc[t] = __builtin_amdgcn_mfma_f32_16x16x32_bf16(afr3, b3, acc[t], 0, 0, 0);
    }

    // epilogue: bias, store f32, BN partial stats (channel c = t*16+lm)
    __shared__ float red[4][CHID];  // 4 KB
    float ps[16], pq[16];
#pragma unroll
    for (int t = 0; t < 16; ++t) {
        float bb = b1[t * 16 + lm];
        float s = 0.f, q = 0.f;
#pragma unroll
        for (int r = 0; r < 4; ++r) {
            float h = acc[t][r] + bb;
            h1[(size_t)(rowBase + lg * 4 + r) * CHID + t * 16 + lm] = h;
            s += h; q += h * h;
        }
        // reduce over lane-groups (rows) for this channel: xor 16, 32
        s += __shfl_xor(s, 16); s += __shfl_xor(s, 32);
        q += __shfl_xor(q, 16); q += __shfl_xor(q, 32);
        ps[t] = s; pq[t] = q;
    }
    if (l < 16) {
#pragma unroll
        for (int t = 0; t < 16; ++t) red[wv][t * 16 + l] = ps[t];
    }
    __syncthreads();
    {
        float v = red[0][tid & 255] + red[1][tid & 255] + red[2][tid & 255] + red[3][tid & 255];
        atomicAdd(&stats[tid], v);
    }
    __syncthreads();
    if (l < 16) {
#pragma unroll
        for (int t = 0; t < 16; ++t) red[wv][t * 16 + l] = pq[t];
    }
    __syncthreads();
    {
        float v = red[0][tid & 255] + red[1][tid & 255] + red[2][tid & 255] + red[3][tid & 255];
        atomicAdd(&stats[CHID + tid], v);
    }
}

// ---------------------------------------------------------------------------
// BN prep: per-channel affine a*h+bb equivalent to BN(gamma,beta)
// ---------------------------------------------------------------------------
__global__ __launch_bounds__(256) void bnprep_kernel(const float* __restrict__ stats,
                                                     const float* __restrict__ gamma,
                                                     const float* __restrict__ beta,
                                                     float* __restrict__ ab) {
    int c = threadIdx.x;
    float mean = stats[c] * (1.0f / N_NODES);
    float var = stats[CHID + c] * (1.0f / N_NODES) - mean * mean;
    float a = gamma[c] / sqrtf(var + 1e-5f);
    ab[c] = a;
    ab[CHID + c] = beta[c] - mean * a;
}

// ---------------------------------------------------------------------------
// GEMM2 (MFMA): g2[m][o] = bf16( dinv[m] * (relu(a*h1+bb) @ W2)[m][o] )
// A built in-register: load h1 f32, affine+relu, pack bf16. 8 ksteps x 8 MFMA.
// ---------------------------------------------------------------------------
__global__ __launch_bounds__(256) void gemm2_kernel(const float* __restrict__ h1,
                                                    const float* __restrict__ ab,
                                                    const unsigned short* __restrict__ w2t,
                                                    const float* __restrict__ dinv,
                                                    unsigned short* __restrict__ g2) {
    int tid = threadIdx.x, wv = tid >> 6, l = tid & 63;
    int rowBase = blockIdx.x * 64 + wv * 16;
    int lm = l & 15, lg = l >> 4;

    f32x4 acc[8];
#pragma unroll
    for (int t = 0; t < 8; ++t) acc[t] = (f32x4){0.f, 0.f, 0.f, 0.f};

    const float* hp = h1 + (size_t)(rowBase + lm) * CHID + lg * 8;
    const unsigned short* wb = w2t + (size_t)lm * CHID + lg * 8;

#pragma unroll
    for (int s = 0; s < 8; ++s) {
        int k0 = s * 32 + lg * 8;
        float4 h0 = *(const float4*)(hp + s * 32);
        float4 h1v = *(const float4*)(hp + s * 32 + 4);
        float4 a0 = *(const float4*)(&ab[k0]);
        float4 a1 = *(const float4*)(&ab[k0 + 4]);
        float4 c0 = *(const float4*)(&ab[CHID + k0]);
        float4 c1 = *(const float4*)(&ab[CHID + k0 + 4]);
        bf16x8 afr;
        afr[0] = (short)f2bf(fmaxf(h0.x * a0.x + c0.x, 0.f));
        afr[1] = (short)f2bf(fmaxf(h0.y * a0.y + c0.y, 0.f));
        afr[2] = (short)f2bf(fmaxf(h0.z * a0.z + c0.z, 0.f));
        afr[3] = (short)f2bf(fmaxf(h0.w * a0.w + c0.w, 0.f));
        afr[4] = (short)f2bf(fmaxf(h1v.x * a1.x + c1.x, 0.f));
        afr[5] = (short)f2bf(fmaxf(h1v.y * a1.y + c1.y, 0.f));
        afr[6] = (short)f2bf(fmaxf(h1v.z * a1.z + c1.z, 0.f));
        afr[7] = (short)f2bf(fmaxf(h1v.w * a1.w + c1.w, 0.f));
#pragma unroll
        for (int t = 0; t < 8; ++t) {
            bf16x8 bfr = *(const bf16x8*)(wb + (size_t)t * 16 * CHID + s * 32);
            acc[t] = __builtin_amdgcn_mfma_f32_16x16x32_bf16(afr, bfr, acc[t], 0, 0, 0);
        }
    }

    float dv0 = dinv[rowBase + lg * 4 + 0];
    float dv1 = dinv[rowBase + lg * 4 + 1];
    float dv2 = dinv[rowBase + lg * 4 + 2];
    float dv3 = dinv[rowBase + lg * 4 + 3];
#pragma unroll
    for (int t = 0; t < 8; ++t) {
        g2[(size_t)(rowBase + lg * 4 + 0) * COUT + t * 16 + lm] = f2bf(dv0 * acc[t][0]);
        g2[(size_t)(rowBase + lg * 4 + 1) * COUT + t * 16 + lm] = f2bf(dv1 * acc[t][1]);
        g2[(size_t)(rowBase + lg * 4 + 2) * COUT + t * 16 + lm] = f2bf(dv2 * acc[t][2]);
        g2[(size_t)(rowBase + lg * 4 + 3) * COUT + t * 16 + lm] = f2bf(dv3 * acc[t][3]);
    }
}

// ---------------------------------------------------------------------------
// AGG2: out[i] = dinv[i]*(sum g2[src] + g2[i]) + b2
// prefetched 8-deep pipeline (256B rows, ushort2 = 4B/lane).
// ---------------------------------------------------------------------------
__global__ __launch_bounds__(256) void agg2_kernel(const unsigned short* __restrict__ g2,
                                                   const int* __restrict__ offs,
                                                   const int* __restrict__ csr,
                                                   const float* __restrict__ dinv,
                                                   const float* __restrict__ b2,
                                                   float* __restrict__ out) {
    int tid = threadIdx.x, wave = tid >> 6, lane = tid & 63;
    int c0 = lane * 2;
    float2 b = *(const float2*)(&b2[c0]);

    for (int g = blockIdx.x; g < N_NODES / 4; g += gridDim.x) {
        int node = g * 4 + wave;
        int s0 = offs[node], s1 = offs[node + 1];
        ushort2 sv = *(const ushort2*)(&g2[(size_t)node * COUT + c0]);  // self loop
        float2 acc;
        acc.x = bf2f(sv.x); acc.y = bf2f(sv.y);

        int nb = (s1 - s0) >> 3;
        int d = s0;
        int i0 = 0, i1 = 0, i2 = 0, i3 = 0, i4 = 0, i5 = 0, i6 = 0, i7 = 0;
        if (nb > 0) {
            i0 = csr[d + 0]; i1 = csr[d + 1]; i2 = csr[d + 2]; i3 = csr[d + 3];
            i4 = csr[d + 4]; i5 = csr[d + 5]; i6 = csr[d + 6]; i7 = csr[d + 7];
        }
        for (int t = 0; t < nb; ++t) {
            ushort2 v0 = *(const ushort2*)(&g2[(size_t)i0 * COUT + c0]);
            ushort2 v1 = *(const ushort2*)(&g2[(size_t)i1 * COUT + c0]);
            ushort2 v2 = *(const ushort2*)(&g2[(size_t)i2 * COUT + c0]);
            ushort2 v3 = *(const ushort2*)(&g2[(size_t)i3 * COUT + c0]);
            ushort2 v4 = *(const ushort2*)(&g2[(size_t)i4 * COUT + c0]);
            ushort2 v5 = *(const ushort2*)(&g2[(size_t)i5 * COUT + c0]);
            ushort2 v6 = *(const ushort2*)(&g2[(size_t)i6 * COUT + c0]);
            ushort2 v7 = *(const ushort2*)(&g2[(size_t)i7 * COUT + c0]);
            int nd = d + 8;
            int j0 = 0, j1 = 0, j2 = 0, j3 = 0, j4 = 0, j5 = 0, j6 = 0, j7 = 0;
            if (t + 1 < nb) {
                j0 = csr[nd + 0]; j1 = csr[nd + 1]; j2 = csr[nd + 2]; j3 = csr[nd + 3];
                j4 = csr[nd + 4]; j5 = csr[nd + 5]; j6 = csr[nd + 6]; j7 = csr[nd + 7];
            }
            acc.x += ((bf2f(v0.x) + bf2f(v1.x)) + (bf2f(v2.x) + bf2f(v3.x))) +
                     ((bf2f(v4.x) + bf2f(v5.x)) + (bf2f(v6.x) + bf2f(v7.x)));
            acc.y += ((bf2f(v0.y) + bf2f(v1.y)) + (bf2f(v2.y) + bf2f(v3.y))) +
                     ((bf2f(v4.y) + bf2f(v5.y)) + (bf2f(v6.y) + bf2f(v7.y)));
            d = nd;
            i0 = j0; i1 = j1; i2 = j2; i3 = j3; i4 = j4; i5 = j5; i6 = j6; i7 = j7;
        }
        for (; d + 4 <= s1; d += 4) {
            int k0 = csr[d + 0], k1 = csr[d + 1], k2 = csr[d + 2], k3 = csr[d + 3];
            ushort2 v0 = *(const ushort2*)(&g2[(size_t)k0 * COUT + c0]);
            ushort2 v1 = *(const ushort2*)(&g2[(size_t)k1 * COUT + c0]);
            ushort2 v2 = *(const ushort2*)(&g2[(size_t)k2 * COUT + c0]);
            ushort2 v3 = *(const ushort2*)(&g2[(size_t)k3 * COUT + c0]);
            acc.x += (bf2f(v0.x) + bf2f(v1.x)) + (bf2f(v2.x) + bf2f(v3.x));
            acc.y += (bf2f(v0.y) + bf2f(v1.y)) + (bf2f(v2.y) + bf2f(v3.y));
        }
        for (; d < s1; ++d) {
            int s = csr[d];
            ushort2 v = *(const ushort2*)(&g2[(size_t)s * COUT + c0]);
            acc.x += bf2f(v.x); acc.y += bf2f(v.y);
        }
        float dv = dinv[node];
        float2 o;
        o.x = acc.x * dv + b.x;
        o.y = acc.y * dv + b.y;
        *(float2*)(&out[(size_t)node * COUT + c0]) = o;
    }
}

// ---------------------------------------------------------------------------
extern "C" void kernel_launch(void* const* d_in, const int* in_sizes, int n_in,
                              void* d_out, int out_size, void* d_ws, size_t ws_size,
                              hipStream_t stream) {
    const float* x     = (const float*)d_in[0];
    const int*   ei    = (const int*)d_in[1];
    const float* W1    = (const float*)d_in[2];
    const float* b1    = (const float*)d_in[3];
    const float* gamma = (const float*)d_in[4];
    const float* beta  = (const float*)d_in[5];
    const float* W2    = (const float*)d_in[6];
    const float* b2    = (const float*)d_in[7];
    float* out = (float*)d_out;

    const int* srcv = ei;            // edge_index[0]
    const int* dstv = ei + E_EDGES;  // edge_index[1]

    // workspace layout (g2 aliases xq: xq dead after aggx)
    char* ws = (char*)d_ws;
    size_t off = 0;
    auto alloc = [&](size_t bytes) -> void* {
        void* p = ws + off;
        off += (bytes + 255) & ~(size_t)255;
        return p;
    };
    int*   deg    = (int*)alloc((size_t)N_NODES * 4);
    int*   offs   = (int*)alloc((size_t)(N_NODES + 1) * 4);
    int*   rank   = (int*)alloc((size_t)E_EDGES * 4);
    float* dinv   = (float*)alloc((size_t)N_NODES * 4);
    int*   csr    = (int*)alloc((size_t)E_EDGES * 4);
    unsigned short* xq  = (unsigned short*)alloc((size_t)N_NODES * CIN * 2);  // 8 MB, also g2
    unsigned short* uq  = (unsigned short*)alloc((size_t)N_NODES * CIN * 2);  // 8 MB
    float* h1     = (float*)alloc((size_t)N_NODES * CHID * 4);                // 32 MB
    unsigned short* w1t = (unsigned short*)alloc((size_t)CHID * CIN * 2);     // 64 KB
    unsigned short* w2t = (unsigned short*)alloc((size_t)COUT * CHID * 2);    // 64 KB
    float* stats  = (float*)alloc(2 * CHID * 4);
    float* ab     = (float*)alloc(2 * CHID * 4);
    unsigned short* g2 = xq;

    hipMemsetAsync(deg, 0, (size_t)N_NODES * 4, stream);
    hipMemsetAsync(stats, 0, 2 * CHID * 4, stream);

    deg_kernel<<<E_EDGES / 2 / 256, 256, 0, stream>>>(dstv, deg, rank);
    scan_kernel<<<1, 1024, 0, stream>>>(deg, offs, dinv);
    fill_kernel<<<E_EDGES / 4 / 256, 256, 0, stream>>>(srcv, dstv, rank, offs, csr);

    quantx_kernel<<<N_NODES * CIN / 4 / 256, 256, 0, stream>>>(x, dinv, xq);
    quantw_kernel<<<(CHID * CIN + COUT * CHID) / 256, 256, 0, stream>>>(W1, W2, w1t, w2t);
    aggx_kernel<<<2048, 256, 0, stream>>>(xq, offs, csr, dinv, uq);
    gemm1_kernel<<<N_NODES / 64, 256, 0, stream>>>(uq, w1t, b1, h1, stats);
    bnprep_kernel<<<1, 256, 0, stream>>>(stats, gamma, beta, ab);
    gemm2_kernel<<<N_NODES / 64, 256, 0, stream>>>(h1, ab, w2t, dinv, g2);
    agg2_kernel<<<2048, 256, 0, stream>>>(g2, offs, csr, dinv, b2, out);
}